// Round 1
// baseline (4843.181 us; speedup 1.0000x reference)
//
#include <hip/hip_runtime.h>
#include <hip/hip_bf16.h>
#include <cstdint>
#include <cstddef>

namespace {
constexpr int B = 512, S = 200, D = 256, H = 4, DH = 64, NI = 100000;
constexpr float EPS = 1e-3f;
constexpr float SCALE = 0.125f;  // 1/sqrt(DH)
}

// ---------------- embedding gather + positional add ----------------
__global__ void embed_k(const int* __restrict__ ids, const float* __restrict__ ie,
                        const float* __restrict__ pe, float* __restrict__ seq) {
  const int total = B * S * (D / 4);
  for (int i = blockIdx.x * blockDim.x + threadIdx.x; i < total; i += gridDim.x * blockDim.x) {
    const int bs = i >> 6;          // D/4 = 64 float4 per row
    const int d4 = (i & 63) << 2;
    const int id = ids[bs];
    const int s = bs % S;
    float4 a = *(const float4*)(ie + (size_t)id * D + d4);
    const float4 p = *(const float4*)(pe + (size_t)s * D + d4);
    a.x += p.x; a.y += p.y; a.z += p.z; a.w += p.w;
    *(float4*)(seq + (size_t)bs * D + d4) = a;
  }
}

// ---------------- wave-per-row LayerNorm (D=256, 64 lanes x float4) ----------
// out[row] = ln(in[row]) * g + b  (+ res[row] if res != nullptr)
__global__ __launch_bounds__(256) void ln_k(const float* __restrict__ in, size_t in_stride,
                                            const float* __restrict__ g, const float* __restrict__ b,
                                            const float* __restrict__ res, float* __restrict__ outp,
                                            int nrows) {
  const int row = blockIdx.x * 4 + (threadIdx.x >> 6);
  if (row >= nrows) return;
  const int lane = threadIdx.x & 63;
  const float4 v = *(const float4*)(in + (size_t)row * in_stride + (lane << 2));
  float s = v.x + v.y + v.z + v.w;
  float ss = v.x * v.x + v.y * v.y + v.z * v.z + v.w * v.w;
#pragma unroll
  for (int off = 32; off; off >>= 1) {
    s += __shfl_xor(s, off);
    ss += __shfl_xor(ss, off);
  }
  const float mean = s * (1.f / D);
  const float rs = rsqrtf(ss * (1.f / D) - mean * mean + EPS);
  const float4 gv = *(const float4*)(g + (lane << 2));
  const float4 bv = *(const float4*)(b + (lane << 2));
  float4 o;
  o.x = (v.x - mean) * rs * gv.x + bv.x;
  o.y = (v.y - mean) * rs * gv.y + bv.y;
  o.z = (v.z - mean) * rs * gv.z + bv.z;
  o.w = (v.w - mean) * rs * gv.w + bv.w;
  if (res) {
    const float4 r = *(const float4*)(res + (size_t)row * D + (lane << 2));
    o.x += r.x; o.y += r.y; o.z += r.z; o.w += r.w;
  }
  *(float4*)(outp + (size_t)row * D + (lane << 2)) = o;
}

// ---------------- seq = (y + x2) * mask ----------------
__global__ void upd_k(const float* __restrict__ y, const float* __restrict__ x2,
                      const int* __restrict__ ids, float* __restrict__ seq) {
  const int total = B * S * (D / 4);
  for (int i = blockIdx.x * blockDim.x + threadIdx.x; i < total; i += gridDim.x * blockDim.x) {
    const int bs = i >> 6;
    const int d4 = (i & 63) << 2;
    const float m = (ids[bs] != NI) ? 1.f : 0.f;
    const float4 a = *(const float4*)(y + (size_t)bs * D + d4);
    const float4 c = *(const float4*)(x2 + (size_t)bs * D + d4);
    float4 o;
    o.x = (a.x + c.x) * m;
    o.y = (a.y + c.y) * m;
    o.z = (a.z + c.z) * m;
    o.w = (a.w + c.w) * m;
    *(float4*)(seq + (size_t)bs * D + d4) = o;
  }
}

// ---------------- tiled fp32 GEMM: C[M,N] = A[M,256] @ W (+bias) -----------
// BT=0: W is [256,N] (C = A@W). BT=1: W is [N,256] (C = A@W^T).
// M, N tiles: 64x64, K-chunk 16, 256 threads, 4x4 micro-tile per thread.
template <int BT, int RELU>
__global__ __launch_bounds__(256) void gemm_k(const float* __restrict__ A,
                                              const float* __restrict__ W,
                                              const float* __restrict__ bias,
                                              float* __restrict__ C, int M, int N) {
  constexpr int K = 256;
  __shared__ float As[16][68];
  __shared__ float Bs[16][68];
  const int tid = threadIdx.x;
  const int tx = tid & 15;   // n-group
  const int ty = tid >> 4;   // m-group
  const int m0 = blockIdx.y * 64;
  const int n0 = blockIdx.x * 64;
  float acc[4][4] = {};
  for (int k0 = 0; k0 < K; k0 += 16) {
    {  // A tile 64x16 -> As[k][m]
      const int r = tid >> 2;
      const int c = (tid & 3) << 2;
      const float4 av = *(const float4*)(A + (size_t)(m0 + r) * K + k0 + c);
      As[c + 0][r] = av.x; As[c + 1][r] = av.y; As[c + 2][r] = av.z; As[c + 3][r] = av.w;
    }
    if constexpr (BT) {  // W[N,K] tile -> Bs[k][n]
      const int n = tid >> 2;
      const int c = (tid & 3) << 2;
      float4 wv = make_float4(0.f, 0.f, 0.f, 0.f);
      if (n0 + n < N) wv = *(const float4*)(W + (size_t)(n0 + n) * K + k0 + c);
      Bs[c + 0][n] = wv.x; Bs[c + 1][n] = wv.y; Bs[c + 2][n] = wv.z; Bs[c + 3][n] = wv.w;
    } else {  // W[K,N] tile -> Bs[k][n]
      const int r = tid >> 4;
      const int c = (tid & 15) << 2;
      const float4 wv = *(const float4*)(W + (size_t)(k0 + r) * N + n0 + c);
      *(float4*)&Bs[r][c] = wv;
    }
    __syncthreads();
#pragma unroll
    for (int k = 0; k < 16; ++k) {
      const float4 a4 = *(const float4*)&As[k][ty << 2];
      const float4 b4 = *(const float4*)&Bs[k][tx << 2];
      const float a[4] = {a4.x, a4.y, a4.z, a4.w};
      const float bb[4] = {b4.x, b4.y, b4.z, b4.w};
#pragma unroll
      for (int i = 0; i < 4; ++i)
#pragma unroll
        for (int j = 0; j < 4; ++j) acc[i][j] += a[i] * bb[j];
    }
    __syncthreads();
  }
  const int n = n0 + (tx << 2);
  if (n >= N) return;
  float bias4[4] = {0.f, 0.f, 0.f, 0.f};
  if (bias) {
    const float4 bv = *(const float4*)(bias + n);
    bias4[0] = bv.x; bias4[1] = bv.y; bias4[2] = bv.z; bias4[3] = bv.w;
  }
#pragma unroll
  for (int i = 0; i < 4; ++i) {
    const int m = m0 + (ty << 2) + i;
    float4 o;
    o.x = acc[i][0] + bias4[0];
    o.y = acc[i][1] + bias4[1];
    o.z = acc[i][2] + bias4[2];
    o.w = acc[i][3] + bias4[3];
    if constexpr (RELU) {
      o.x = fmaxf(o.x, 0.f); o.y = fmaxf(o.y, 0.f);
      o.z = fmaxf(o.z, 0.f); o.w = fmaxf(o.w, 0.f);
    }
    *(float4*)(C + (size_t)m * N + n) = o;
  }
}

// ---------------- fused causal attention, one block per (b,h) --------------
// K,V staged in LDS (stride 65 -> conflict-free), wave-per-query, P in LDS.
__global__ __launch_bounds__(256) void attn_k(const float* __restrict__ Q,
                                              const float* __restrict__ Kg,
                                              const float* __restrict__ Vg,
                                              float* __restrict__ O) {
  __shared__ float Ks[S][DH + 1];
  __shared__ float Vs[S][DH + 1];
  __shared__ float Ps[4][S];
  const int b = blockIdx.x >> 2;  // H=4
  const int h = blockIdx.x & 3;
  const int tid = threadIdx.x, wave = tid >> 6, lane = tid & 63;
  const size_t base = (size_t)b * S * D + h * DH;
  for (int idx = tid; idx < S * DH; idx += 256) {
    const int j = idx >> 6, d = idx & 63;
    Ks[j][d] = Kg[base + (size_t)j * D + d];
    Vs[j][d] = Vg[base + (size_t)j * D + d];
  }
  __syncthreads();
  for (int qi = wave; qi < S; qi += 4) {
    const float* qrow = Q + base + (size_t)qi * D;
    const int nk = qi + 1;
    const int rounds = (nk + 63) >> 6;
    float sc[4];
    float mloc = -3.0e38f;
    for (int r = 0; r < rounds; ++r) {
      const int j = r * 64 + lane;
      float s = -3.0e38f;
      if (j < nk) {
        float acc = 0.f;
#pragma unroll
        for (int d = 0; d < DH; d += 4) {
          const float4 qv = *(const float4*)(qrow + d);
          acc += qv.x * Ks[j][d] + qv.y * Ks[j][d + 1] + qv.z * Ks[j][d + 2] + qv.w * Ks[j][d + 3];
        }
        s = acc * SCALE;
      }
      sc[r] = s;
      mloc = fmaxf(mloc, s);
    }
#pragma unroll
    for (int off = 32; off; off >>= 1) mloc = fmaxf(mloc, __shfl_xor(mloc, off));
    float sloc = 0.f;
    for (int r = 0; r < rounds; ++r) {
      const int j = r * 64 + lane;
      if (j < nk) {
        const float e = __expf(sc[r] - mloc);
        Ps[wave][j] = e;
        sloc += e;
      }
    }
#pragma unroll
    for (int off = 32; off; off >>= 1) sloc += __shfl_xor(sloc, off);
    const float inv = 1.f / sloc;
    float acc = 0.f;
    for (int j = 0; j < nk; ++j) acc += Ps[wave][j] * Vs[j][lane];
    O[base + (size_t)qi * D + lane] = acc * inv;
  }
}

// ---------------------------------------------------------------------------
extern "C" void kernel_launch(void* const* d_in, const int* in_sizes, int n_in,
                              void* d_out, int out_size, void* d_ws, size_t ws_size,
                              hipStream_t stream) {
  const int* ids        = (const int*)d_in[0];
  const float* item_emb = (const float*)d_in[1];
  const float* pos_emb  = (const float*)d_in[2];
  const float* ln1_g    = (const float*)d_in[3];
  const float* ln1_b    = (const float*)d_in[4];
  const float* wq       = (const float*)d_in[5];
  const float* bq       = (const float*)d_in[6];
  const float* wk       = (const float*)d_in[7];
  const float* bk       = (const float*)d_in[8];
  const float* wv       = (const float*)d_in[9];
  const float* bv       = (const float*)d_in[10];
  const float* ln2_g    = (const float*)d_in[11];
  const float* ln2_b    = (const float*)d_in[12];
  const float* wd       = (const float*)d_in[13];
  const float* bd       = (const float*)d_in[14];
  const float* seq_g    = (const float*)d_in[15];
  const float* seq_b    = (const float*)d_in[16];
  const float* w_out    = (const float*)d_in[17];
  float* out = (float*)d_out;

  // workspace: 5 buffers of [B,S,D] f32 + seq_emb [B,D]  (~525 MB)
  const size_t BUF = (size_t)B * S * D;  // elements
  float* seq  = (float*)d_ws;
  float* xq   = seq + BUF;
  float* xk   = xq + BUF;
  float* xv   = xk + BUF;
  float* xo   = xv + BUF;   // holds: ln1(seq) tmp -> attn out -> x2
  float* semb = xo + BUF;

  const int M = B * S;           // 102400
  const dim3 gemm_grid(D / 64, M / 64);  // (4, 1600)
  const int ln_grid = (M + 3) / 4;

  embed_k<<<2048, 256, 0, stream>>>(ids, item_emb, pos_emb, seq);

  for (int blk = 0; blk < 2; ++blk) {
    const float* l1g = ln1_g + blk * D;
    const float* l1b = ln1_b + blk * D;
    const float* l2g = ln2_g + blk * D;
    const float* l2b = ln2_b + blk * D;
    const float* Wq = wq + (size_t)blk * D * D;
    const float* Wk = wk + (size_t)blk * D * D;
    const float* Wv = wv + (size_t)blk * D * D;
    const float* Wd = wd + (size_t)blk * D * D;

    // k = seq@Wk + bk ; v = seq@Wv + bv
    gemm_k<0, 0><<<gemm_grid, 256, 0, stream>>>(seq, Wk, bk + blk * D, xk, M, D);
    gemm_k<0, 0><<<gemm_grid, 256, 0, stream>>>(seq, Wv, bv + blk * D, xv, M, D);
    // tmp = ln1(seq) -> xo ; q = tmp@Wq + bq -> xq
    ln_k<<<ln_grid, 256, 0, stream>>>(seq, D, l1g, l1b, nullptr, xo, M);
    gemm_k<0, 0><<<gemm_grid, 256, 0, stream>>>(xo, Wq, bq + blk * D, xq, M, D);
    // attention: o -> xo (overwrites tmp; tmp recomputed below)
    attn_k<<<B * H, 256, 0, stream>>>(xq, xk, xv, xo);
    // x2 = o + ln1(seq) -> xo (in place)
    ln_k<<<ln_grid, 256, 0, stream>>>(seq, D, l1g, l1b, xo, xo, M);
    // t = ln2(x2) -> xq
    ln_k<<<ln_grid, 256, 0, stream>>>(xo, D, l2g, l2b, nullptr, xq, M);
    // y = relu(t@Wd + bd) -> xk
    gemm_k<0, 1><<<gemm_grid, 256, 0, stream>>>(xq, Wd, bd + blk * D, xk, M, D);
    // seq = (y + x2) * mask
    upd_k<<<2048, 256, 0, stream>>>(xk, xo, ids, seq);
  }

  // seq_emb = ln(seq[:, -1, :])
  ln_k<<<(B + 3) / 4, 256, 0, stream>>>(seq + (size_t)(S - 1) * D, (size_t)S * D,
                                        seq_g, seq_b, nullptr, semb, B);
  // logits = seq_emb @ out_item_emb^T
  const dim3 fgrid((NI + 63) / 64, B / 64);  // (1563, 8)
  gemm_k<1, 0><<<fgrid, 256, 0, stream>>>(semb, w_out, nullptr, out, B, NI);
}

// Round 2
// 2498.185 us; speedup vs baseline: 1.9387x; 1.9387x over previous
//
#include <hip/hip_runtime.h>
#include <hip/hip_bf16.h>
#include <cstdint>
#include <cstddef>

namespace {
constexpr int B = 512, S = 200, D = 256, H = 4, DH = 64, NI = 100000;
constexpr float EPS = 1e-3f;
constexpr float SCALE = 0.125f;  // 1/sqrt(DH)
}

typedef __attribute__((ext_vector_type(8))) short bf16x8;
typedef __attribute__((ext_vector_type(4))) float f32x4;
typedef __attribute__((ext_vector_type(8))) unsigned short ushort8;

__device__ inline unsigned short f2b(float f) {
  union { float f; unsigned int u; } v; v.f = f;
  unsigned int r = v.u + 0x7FFFu + ((v.u >> 16) & 1u);
  return (unsigned short)(r >> 16);
}

__device__ inline bf16x8 pack8(float4 a, float4 b) {
  bf16x8 r;
  r[0] = (short)f2b(a.x); r[1] = (short)f2b(a.y); r[2] = (short)f2b(a.z); r[3] = (short)f2b(a.w);
  r[4] = (short)f2b(b.x); r[5] = (short)f2b(b.y); r[6] = (short)f2b(b.z); r[7] = (short)f2b(b.w);
  return r;
}

// ---------------- embedding gather + positional add ----------------
__global__ void embed_k(const int* __restrict__ ids, const float* __restrict__ ie,
                        const float* __restrict__ pe, float* __restrict__ seq) {
  const int total = B * S * (D / 4);
  for (int i = blockIdx.x * blockDim.x + threadIdx.x; i < total; i += gridDim.x * blockDim.x) {
    const int bs = i >> 6;          // D/4 = 64 float4 per row
    const int d4 = (i & 63) << 2;
    const int id = ids[bs];
    const int s = bs % S;
    float4 a = *(const float4*)(ie + (size_t)id * D + d4);
    const float4 p = *(const float4*)(pe + (size_t)s * D + d4);
    a.x += p.x; a.y += p.y; a.z += p.z; a.w += p.w;
    *(float4*)(seq + (size_t)bs * D + d4) = a;
  }
}

// ---------------- wave-per-row LayerNorm (D=256, 64 lanes x float4) ----------
__global__ __launch_bounds__(256) void ln_k(const float* __restrict__ in, size_t in_stride,
                                            const float* __restrict__ g, const float* __restrict__ b,
                                            const float* __restrict__ res, float* __restrict__ outp,
                                            int nrows) {
  const int row = blockIdx.x * 4 + (threadIdx.x >> 6);
  if (row >= nrows) return;
  const int lane = threadIdx.x & 63;
  const float4 v = *(const float4*)(in + (size_t)row * in_stride + (lane << 2));
  float s = v.x + v.y + v.z + v.w;
  float ss = v.x * v.x + v.y * v.y + v.z * v.z + v.w * v.w;
#pragma unroll
  for (int off = 32; off; off >>= 1) {
    s += __shfl_xor(s, off);
    ss += __shfl_xor(ss, off);
  }
  const float mean = s * (1.f / D);
  const float rs = rsqrtf(ss * (1.f / D) - mean * mean + EPS);
  const float4 gv = *(const float4*)(g + (lane << 2));
  const float4 bv = *(const float4*)(b + (lane << 2));
  float4 o;
  o.x = (v.x - mean) * rs * gv.x + bv.x;
  o.y = (v.y - mean) * rs * gv.y + bv.y;
  o.z = (v.z - mean) * rs * gv.z + bv.z;
  o.w = (v.w - mean) * rs * gv.w + bv.w;
  if (res) {
    const float4 r = *(const float4*)(res + (size_t)row * D + (lane << 2));
    o.x += r.x; o.y += r.y; o.z += r.z; o.w += r.w;
  }
  *(float4*)(outp + (size_t)row * D + (lane << 2)) = o;
}

// ---------------- seq = (y + x2) * mask ----------------
__global__ void upd_k(const float* __restrict__ y, const float* __restrict__ x2,
                      const int* __restrict__ ids, float* __restrict__ seq) {
  const int total = B * S * (D / 4);
  for (int i = blockIdx.x * blockDim.x + threadIdx.x; i < total; i += gridDim.x * blockDim.x) {
    const int bs = i >> 6;
    const int d4 = (i & 63) << 2;
    const float m = (ids[bs] != NI) ? 1.f : 0.f;
    const float4 a = *(const float4*)(y + (size_t)bs * D + d4);
    const float4 c = *(const float4*)(x2 + (size_t)bs * D + d4);
    float4 o;
    o.x = (a.x + c.x) * m;
    o.y = (a.y + c.y) * m;
    o.z = (a.z + c.z) * m;
    o.w = (a.w + c.w) * m;
    *(float4*)(seq + (size_t)bs * D + d4) = o;
  }
}

// ---------------- tiled fp32 GEMM: C[M,N] = A[M,256] @ W (+bias) -----------
template <int BT, int RELU>
__global__ __launch_bounds__(256) void gemm_k(const float* __restrict__ A,
                                              const float* __restrict__ W,
                                              const float* __restrict__ bias,
                                              float* __restrict__ C, int M, int N) {
  constexpr int K = 256;
  __shared__ float As[16][68];
  __shared__ float Bs[16][68];
  const int tid = threadIdx.x;
  const int tx = tid & 15;   // n-group
  const int ty = tid >> 4;   // m-group
  const int m0 = blockIdx.y * 64;
  const int n0 = blockIdx.x * 64;
  float acc[4][4] = {};
  for (int k0 = 0; k0 < K; k0 += 16) {
    {  // A tile 64x16 -> As[k][m]
      const int r = tid >> 2;
      const int c = (tid & 3) << 2;
      const float4 av = *(const float4*)(A + (size_t)(m0 + r) * K + k0 + c);
      As[c + 0][r] = av.x; As[c + 1][r] = av.y; As[c + 2][r] = av.z; As[c + 3][r] = av.w;
    }
    if constexpr (BT) {  // W[N,K] tile -> Bs[k][n]
      const int n = tid >> 2;
      const int c = (tid & 3) << 2;
      float4 wv = make_float4(0.f, 0.f, 0.f, 0.f);
      if (n0 + n < N) wv = *(const float4*)(W + (size_t)(n0 + n) * K + k0 + c);
      Bs[c + 0][n] = wv.x; Bs[c + 1][n] = wv.y; Bs[c + 2][n] = wv.z; Bs[c + 3][n] = wv.w;
    } else {  // W[K,N] tile -> Bs[k][n]
      const int r = tid >> 4;
      const int c = (tid & 15) << 2;
      const float4 wv = *(const float4*)(W + (size_t)(k0 + r) * N + n0 + c);
      *(float4*)&Bs[r][c] = wv;
    }
    __syncthreads();
#pragma unroll
    for (int k = 0; k < 16; ++k) {
      const float4 a4 = *(const float4*)&As[k][ty << 2];
      const float4 b4 = *(const float4*)&Bs[k][tx << 2];
      const float a[4] = {a4.x, a4.y, a4.z, a4.w};
      const float bb[4] = {b4.x, b4.y, b4.z, b4.w};
#pragma unroll
      for (int i = 0; i < 4; ++i)
#pragma unroll
        for (int j = 0; j < 4; ++j) acc[i][j] += a[i] * bb[j];
    }
    __syncthreads();
  }
  const int n = n0 + (tx << 2);
  if (n >= N) return;
  float bias4[4] = {0.f, 0.f, 0.f, 0.f};
  if (bias) {
    const float4 bv = *(const float4*)(bias + n);
    bias4[0] = bv.x; bias4[1] = bv.y; bias4[2] = bv.z; bias4[3] = bv.w;
  }
#pragma unroll
  for (int i = 0; i < 4; ++i) {
    const int m = m0 + (ty << 2) + i;
    float4 o;
    o.x = acc[i][0] + bias4[0];
    o.y = acc[i][1] + bias4[1];
    o.z = acc[i][2] + bias4[2];
    o.w = acc[i][3] + bias4[3];
    if constexpr (RELU) {
      o.x = fmaxf(o.x, 0.f); o.y = fmaxf(o.y, 0.f);
      o.z = fmaxf(o.z, 0.f); o.w = fmaxf(o.w, 0.f);
    }
    *(float4*)(C + (size_t)m * N + n) = o;
  }
}

// ---------------- MFMA causal attention, one block per (b,h) ---------------
// K staged bf16 in LDS stride 72 (2-way banks, free). V^T and per-wave P
// staged bf16 stride 232 (2-way banks, free). Full score rows in registers
// (13 f32x4 tiles), wave-parallel softmax via shfl over 16-lane groups,
// P -> LDS -> PV A-fragments. No inter-wave barriers after staging.
__global__ __launch_bounds__(256) void attn_mfma_k(const float* __restrict__ Q,
                                                   const float* __restrict__ Kg,
                                                   const float* __restrict__ Vg,
                                                   float* __restrict__ O) {
  constexpr int KSS = 72, VTS = 232, PSS = 232;
  __shared__ unsigned short Ks[208 * KSS];      // [key j][d]   (rows 200..207 garbage, masked)
  __shared__ unsigned short Vt[64 * VTS];       // [d][key j]   (cols 200..223 zeroed)
  __shared__ unsigned short Ps[4 * 16 * PSS];   // per-wave P [row][k] (cols 208..223 zeroed)
  const int b = blockIdx.x >> 2;  // H=4
  const int h = blockIdx.x & 3;
  const int tid = threadIdx.x, w = tid >> 6, lane = tid & 63;
  const int kb = lane >> 4;   // k-block of 8 / row-group
  const int ln = lane & 15;
  const size_t base = (size_t)b * S * D + h * DH;

  // ---- stage K as bf16 granules of 8 ----
  for (int g = tid; g < 200 * 8; g += 256) {
    const int row = g >> 3, gr = g & 7;
    const float* src = Kg + base + (size_t)row * D + gr * 8;
    const float4 f0 = *(const float4*)src;
    const float4 f1 = *(const float4*)(src + 4);
    *(bf16x8*)(Ks + row * KSS + gr * 8) = pack8(f0, f1);
  }
  // ---- stage V transposed ----
  for (int idx = tid; idx < 200 * 16; idx += 256) {
    const int row = idx >> 4, dq = idx & 15;
    const float4 f = *(const float4*)(Vg + base + (size_t)row * D + dq * 4);
    Vt[(dq * 4 + 0) * VTS + row] = f2b(f.x);
    Vt[(dq * 4 + 1) * VTS + row] = f2b(f.y);
    Vt[(dq * 4 + 2) * VTS + row] = f2b(f.z);
    Vt[(dq * 4 + 3) * VTS + row] = f2b(f.w);
  }
  // zero Vt pad cols 200..223 (avoid NaN garbage into MFMA)
  if (tid < 64 * 3) {
    const int d = tid / 3, g = tid % 3;
    *(bf16x8*)(Vt + d * VTS + 200 + g * 8) = (bf16x8)0;
  }
  // zero own-wave P pad cols 208..223
  unsigned short* Pw = Ps + w * 16 * PSS;
  if (lane < 32) {
    const int row = lane >> 1, g = lane & 1;
    *(bf16x8*)(Pw + row * PSS + 208 + g * 8) = (bf16x8)0;
  }
  __syncthreads();

  // ---- per-wave query chunks of 16 rows; no barriers needed ----
  for (int q0 = w * 16; q0 < S; q0 += 64) {
    // A-fragments of Q (fp32 global -> bf16 regs): row = ln, k = kb*8+j (+32)
    int qr = q0 + ln; if (qr > S - 1) qr = S - 1;
    const float* qp = Q + base + (size_t)qr * D + kb * 8;
    bf16x8 aq0, aq1;
    {
      const float4 x0 = *(const float4*)(qp);
      const float4 x1 = *(const float4*)(qp + 4);
      aq0 = pack8(x0, x1);
      const float4 y0 = *(const float4*)(qp + 32);
      const float4 y1 = *(const float4*)(qp + 36);
      aq1 = pack8(y0, y1);
    }
    // ---- QK^T: 13 col-tiles of 16 keys ----
    f32x4 sc[13];
#pragma unroll
    for (int t = 0; t < 13; ++t) {
      const bf16x8 b0 = *(const bf16x8*)(Ks + (t * 16 + ln) * KSS + kb * 8);
      const bf16x8 b1 = *(const bf16x8*)(Ks + (t * 16 + ln) * KSS + 32 + kb * 8);
      f32x4 acc = {0.f, 0.f, 0.f, 0.f};
      acc = __builtin_amdgcn_mfma_f32_16x16x32_bf16(aq0, b0, acc, 0, 0, 0);
      acc = __builtin_amdgcn_mfma_f32_16x16x32_bf16(aq1, b1, acc, 0, 0, 0);
      sc[t] = acc;
    }
    // ---- mask + softmax per row-group; write P (bf16) to own LDS ----
    float inv[4];
#pragma unroll
    for (int r = 0; r < 4; ++r) {
      const int q = q0 + kb * 4 + r;
      float m = -1e30f;
#pragma unroll
      for (int t = 0; t < 13; ++t) {
        const int j = t * 16 + ln;
        float s = sc[t][r] * SCALE;
        s = (j <= q) ? s : -1e30f;   // ternary: NaN-safe for garbage K rows
        sc[t][r] = s;
        m = fmaxf(m, s);
      }
      m = fmaxf(m, __shfl_xor(m, 1));
      m = fmaxf(m, __shfl_xor(m, 2));
      m = fmaxf(m, __shfl_xor(m, 4));
      m = fmaxf(m, __shfl_xor(m, 8));
      float sm = 0.f;
#pragma unroll
      for (int t = 0; t < 13; ++t) {
        const float e = __expf(sc[t][r] - m);
        sm += e;
        Pw[(kb * 4 + r) * PSS + t * 16 + ln] = f2b(e);
      }
      sm += __shfl_xor(sm, 1);
      sm += __shfl_xor(sm, 2);
      sm += __shfl_xor(sm, 4);
      sm += __shfl_xor(sm, 8);
      inv[r] = 1.f / sm;
    }
    // ---- PV: 4 d-tiles of 16 cols, k = 7 tiles of 32 ----
#pragma unroll
    for (int ct = 0; ct < 4; ++ct) {
      f32x4 acc = {0.f, 0.f, 0.f, 0.f};
#pragma unroll
      for (int kt = 0; kt < 7; ++kt) {
        const bf16x8 a = *(const bf16x8*)(Pw + ln * PSS + kt * 32 + kb * 8);
        const bf16x8 bb = *(const bf16x8*)(Vt + (ct * 16 + ln) * VTS + kt * 32 + kb * 8);
        acc = __builtin_amdgcn_mfma_f32_16x16x32_bf16(a, bb, acc, 0, 0, 0);
      }
#pragma unroll
      for (int r = 0; r < 4; ++r) {
        const int q = q0 + kb * 4 + r;
        if (q < S) O[base + (size_t)q * D + ct * 16 + ln] = acc[r] * inv[r];
      }
    }
  }
}

// ---------------------------------------------------------------------------
extern "C" void kernel_launch(void* const* d_in, const int* in_sizes, int n_in,
                              void* d_out, int out_size, void* d_ws, size_t ws_size,
                              hipStream_t stream) {
  const int* ids        = (const int*)d_in[0];
  const float* item_emb = (const float*)d_in[1];
  const float* pos_emb  = (const float*)d_in[2];
  const float* ln1_g    = (const float*)d_in[3];
  const float* ln1_b    = (const float*)d_in[4];
  const float* wq       = (const float*)d_in[5];
  const float* bq       = (const float*)d_in[6];
  const float* wk       = (const float*)d_in[7];
  const float* bk       = (const float*)d_in[8];
  const float* wv       = (const float*)d_in[9];
  const float* bv       = (const float*)d_in[10];
  const float* ln2_g    = (const float*)d_in[11];
  const float* ln2_b    = (const float*)d_in[12];
  const float* wd       = (const float*)d_in[13];
  const float* bd       = (const float*)d_in[14];
  const float* seq_g    = (const float*)d_in[15];
  const float* seq_b    = (const float*)d_in[16];
  const float* w_out    = (const float*)d_in[17];
  float* out = (float*)d_out;

  const size_t BUF = (size_t)B * S * D;  // elements
  float* seq  = (float*)d_ws;
  float* xq   = seq + BUF;
  float* xk   = xq + BUF;
  float* xv   = xk + BUF;
  float* xo   = xv + BUF;   // holds: ln1(seq) tmp -> attn out -> x2
  float* semb = xo + BUF;

  const int M = B * S;           // 102400
  const dim3 gemm_grid(D / 64, M / 64);  // (4, 1600)
  const int ln_grid = (M + 3) / 4;

  embed_k<<<2048, 256, 0, stream>>>(ids, item_emb, pos_emb, seq);

  for (int blk = 0; blk < 2; ++blk) {
    const float* l1g = ln1_g + blk * D;
    const float* l1b = ln1_b + blk * D;
    const float* l2g = ln2_g + blk * D;
    const float* l2b = ln2_b + blk * D;
    const float* Wq = wq + (size_t)blk * D * D;
    const float* Wk = wk + (size_t)blk * D * D;
    const float* Wv = wv + (size_t)blk * D * D;
    const float* Wd = wd + (size_t)blk * D * D;

    gemm_k<0, 0><<<gemm_grid, 256, 0, stream>>>(seq, Wk, bk + blk * D, xk, M, D);
    gemm_k<0, 0><<<gemm_grid, 256, 0, stream>>>(seq, Wv, bv + blk * D, xv, M, D);
    ln_k<<<ln_grid, 256, 0, stream>>>(seq, D, l1g, l1b, nullptr, xo, M);
    gemm_k<0, 0><<<gemm_grid, 256, 0, stream>>>(xo, Wq, bq + blk * D, xq, M, D);
    attn_mfma_k<<<B * H, 256, 0, stream>>>(xq, xk, xv, xo);
    ln_k<<<ln_grid, 256, 0, stream>>>(seq, D, l1g, l1b, xo, xo, M);
    ln_k<<<ln_grid, 256, 0, stream>>>(xo, D, l2g, l2b, nullptr, xq, M);
    gemm_k<0, 1><<<gemm_grid, 256, 0, stream>>>(xq, Wd, bd + blk * D, xk, M, D);
    upd_k<<<2048, 256, 0, stream>>>(xk, xo, ids, seq);
  }

  ln_k<<<(B + 3) / 4, 256, 0, stream>>>(seq + (size_t)(S - 1) * D, (size_t)S * D,
                                        seq_g, seq_b, nullptr, semb, B);
  const dim3 fgrid((NI + 63) / 64, B / 64);  // (1563, 8)
  gemm_k<1, 0><<<fgrid, 256, 0, stream>>>(semb, w_out, nullptr, out, B, NI);
}

// Round 3
// 1242.724 us; speedup vs baseline: 3.8972x; 2.0102x over previous
//
#include <hip/hip_runtime.h>
#include <hip/hip_bf16.h>
#include <cstdint>
#include <cstddef>

namespace {
constexpr int B = 512, S = 200, D = 256, H = 4, DH = 64, NI = 100000;
constexpr float EPS = 1e-3f;
constexpr float SCALE = 0.125f;  // 1/sqrt(DH)
}

typedef __attribute__((ext_vector_type(8))) short bf16x8;
typedef __attribute__((ext_vector_type(4))) float f32x4;

__device__ inline unsigned short f2b(float f) {
  union { float f; unsigned int u; } v; v.f = f;
  unsigned int r = v.u + 0x7FFFu + ((v.u >> 16) & 1u);
  return (unsigned short)(r >> 16);
}

__device__ inline bf16x8 pack8(float4 a, float4 b) {
  bf16x8 r;
  r[0] = (short)f2b(a.x); r[1] = (short)f2b(a.y); r[2] = (short)f2b(a.z); r[3] = (short)f2b(a.w);
  r[4] = (short)f2b(b.x); r[5] = (short)f2b(b.y); r[6] = (short)f2b(b.z); r[7] = (short)f2b(b.w);
  return r;
}

__device__ inline ushort4 pack4(float4 a) {
  ushort4 r;
  r.x = f2b(a.x); r.y = f2b(a.y); r.z = f2b(a.z); r.w = f2b(a.w);
  return r;
}

__device__ inline void gload_lds16(const unsigned short* g, unsigned short* l) {
  __builtin_amdgcn_global_load_lds((const __attribute__((address_space(1))) void*)g,
                                   (__attribute__((address_space(3))) void*)l, 16, 0, 0);
}

// ---------------- weight prep: w_out fp32 [NI][256] -> bf16 same layout ----
__global__ void cvt_wout_k(const float* __restrict__ src, unsigned short* __restrict__ dst) {
  const int total = NI * D / 8;  // 3.2M granules
  for (int i = blockIdx.x * blockDim.x + threadIdx.x; i < total; i += gridDim.x * blockDim.x) {
    const float4 a = *(const float4*)(src + (size_t)i * 8);
    const float4 b = *(const float4*)(src + (size_t)i * 8 + 4);
    *(bf16x8*)(dst + (size_t)i * 8) = pack8(a, b);
  }
}

// ------- hidden weights [K][N] fp32 -> WT bf16 [w][N][K], w = blk*4+{q,k,v,d}
__global__ void cvt_wt_k(const float* __restrict__ wq, const float* __restrict__ wk,
                         const float* __restrict__ wv, const float* __restrict__ wd,
                         unsigned short* __restrict__ dst) {
  const int t = blockIdx.x * 256 + threadIdx.x;  // 131072 total
  const int w = t >> 14, rem = t & 16383;
  const int k = rem >> 6, n4 = (rem & 63) * 4;
  const int blk = w >> 2, which = w & 3;
  const float* src = (which == 0 ? wq : which == 1 ? wk : which == 2 ? wv : wd) + blk * 65536;
  const float4 v = *(const float4*)(src + k * 256 + n4);
  unsigned short* d = dst + w * 65536;
  d[(n4 + 0) * 256 + k] = f2b(v.x);
  d[(n4 + 1) * 256 + k] = f2b(v.y);
  d[(n4 + 2) * 256 + k] = f2b(v.z);
  d[(n4 + 3) * 256 + k] = f2b(v.w);
}

// ---------------- embedding gather + positional add (fp32 + bf16 out) ------
__global__ void embed_k(const int* __restrict__ ids, const float* __restrict__ ie,
                        const float* __restrict__ pe, float* __restrict__ seq,
                        unsigned short* __restrict__ seq_bf) {
  const int total = B * S * (D / 4);
  for (int i = blockIdx.x * blockDim.x + threadIdx.x; i < total; i += gridDim.x * blockDim.x) {
    const int bs = i >> 6;
    const int d4 = (i & 63) << 2;
    const int id = ids[bs];
    const int s = bs % S;
    float4 a = *(const float4*)(ie + (size_t)id * D + d4);
    const float4 p = *(const float4*)(pe + (size_t)s * D + d4);
    a.x += p.x; a.y += p.y; a.z += p.z; a.w += p.w;
    *(float4*)(seq + (size_t)bs * D + d4) = a;
    *(ushort4*)(seq_bf + (size_t)bs * D + d4) = pack4(a);
  }
}

// ---------------- wave-per-row LayerNorm, optional fp32/bf16 outs ----------
__global__ __launch_bounds__(256) void ln_k(const float* __restrict__ in, size_t in_stride,
                                            const float* __restrict__ g, const float* __restrict__ b,
                                            const float* __restrict__ res, float* __restrict__ out_f,
                                            unsigned short* __restrict__ out_bf, int nrows) {
  const int row = blockIdx.x * 4 + (threadIdx.x >> 6);
  if (row >= nrows) return;
  const int lane = threadIdx.x & 63;
  const float4 v = *(const float4*)(in + (size_t)row * in_stride + (lane << 2));
  float s = v.x + v.y + v.z + v.w;
  float ss = v.x * v.x + v.y * v.y + v.z * v.z + v.w * v.w;
#pragma unroll
  for (int off = 32; off; off >>= 1) {
    s += __shfl_xor(s, off);
    ss += __shfl_xor(ss, off);
  }
  const float mean = s * (1.f / D);
  const float rs = rsqrtf(ss * (1.f / D) - mean * mean + EPS);
  const float4 gv = *(const float4*)(g + (lane << 2));
  const float4 bv = *(const float4*)(b + (lane << 2));
  float4 o;
  o.x = (v.x - mean) * rs * gv.x + bv.x;
  o.y = (v.y - mean) * rs * gv.y + bv.y;
  o.z = (v.z - mean) * rs * gv.z + bv.z;
  o.w = (v.w - mean) * rs * gv.w + bv.w;
  if (res) {
    const float4 r = *(const float4*)(res + (size_t)row * D + (lane << 2));
    o.x += r.x; o.y += r.y; o.z += r.z; o.w += r.w;
  }
  if (out_f) *(float4*)(out_f + (size_t)row * D + (lane << 2)) = o;
  if (out_bf) *(ushort4*)(out_bf + (size_t)row * D + (lane << 2)) = pack4(o);
}

// ---------------- seq = (y + x2) * mask  (fp32 + bf16 out) -----------------
__global__ void upd_k(const float* __restrict__ y, const float* __restrict__ x2,
                      const int* __restrict__ ids, float* __restrict__ seq,
                      unsigned short* __restrict__ seq_bf) {
  const int total = B * S * (D / 4);
  for (int i = blockIdx.x * blockDim.x + threadIdx.x; i < total; i += gridDim.x * blockDim.x) {
    const int bs = i >> 6;
    const int d4 = (i & 63) << 2;
    const float m = (ids[bs] != NI) ? 1.f : 0.f;
    const float4 a = *(const float4*)(y + (size_t)bs * D + d4);
    const float4 c = *(const float4*)(x2 + (size_t)bs * D + d4);
    float4 o;
    o.x = (a.x + c.x) * m;
    o.y = (a.y + c.y) * m;
    o.z = (a.z + c.z) * m;
    o.w = (a.w + c.w) * m;
    *(float4*)(seq + (size_t)bs * D + d4) = o;
    *(ushort4*)(seq_bf + (size_t)bs * D + d4) = pack4(o);
  }
}

// ---------------- bf16 MFMA GEMM: C[M,N] = A[M,256] @ Wt^T (+bias) ---------
// A bf16 [M][256] row-major; Wt bf16 [N][256] row-major (B^T layout).
// 128x128 tile, BK=64, 4 waves, wave-tile 64x64 (4x4 frags of 16x16x32).
// LDS rows 128 B, XOR-swizzled (byte ^= (row&7)<<4): linear global_load_lds
// dest + inverse-swizzled per-lane global source + swizzled ds_read.
template <int NSWAP, int GUARD, int RELU, int OUTBF>
__global__ __launch_bounds__(256) void bgemm_k(const unsigned short* __restrict__ A,
                                               const unsigned short* __restrict__ Wt,
                                               const float* __restrict__ bias,
                                               void* __restrict__ Cp, int M, int N) {
  __shared__ unsigned short As[128 * 64];
  __shared__ unsigned short Bs[128 * 64];
  const int tid = threadIdx.x, w = tid >> 6, lane = tid & 63;
  const int kb = lane >> 4, ln = lane & 15;
  const int m0 = (NSWAP ? blockIdx.x : blockIdx.y) * 128;
  const int n0 = (NSWAP ? blockIdx.y : blockIdx.x) * 128;
  const int wm = w & 1, wn = w >> 1;
  const int rl = lane >> 3;            // staging: row-within-8
  const int cb = (lane & 7) << 4;      // staging: byte col

  f32x4 acc[4][4];
#pragma unroll
  for (int i = 0; i < 4; ++i)
#pragma unroll
    for (int j = 0; j < 4; ++j) acc[i][j] = (f32x4){0.f, 0.f, 0.f, 0.f};

  for (int ks = 0; ks < 4; ++ks) {
    const int ko = ks * 64;  // ushort offset into each row
#pragma unroll
    for (int c = 0; c < 4; ++c) {
      const int arow = w * 32 + c * 8 + rl;                 // 0..127
      const int sw = (arow & 7) << 4;
      const int cu = (cb ^ sw) >> 1;                        // ushort offset in row chunk
      gload_lds16(A + (size_t)(m0 + arow) * 256 + ko + cu, As + (w * 32 + c * 8) * 64);
      int br = n0 + arow;
      if (GUARD && br > N - 1) br = N - 1;
      gload_lds16(Wt + (size_t)br * 256 + ko + cu, Bs + (w * 32 + c * 8) * 64);
    }
    __syncthreads();
#pragma unroll
    for (int h = 0; h < 2; ++h) {
      bf16x8 af[4], bfr[4];
#pragma unroll
      for (int i = 0; i < 4; ++i) {
        const int ar = wm * 64 + i * 16 + ln;
        af[i] = *(const bf16x8*)(As + ar * 64 + (((h * 64 + kb * 16) ^ ((ar & 7) << 4)) >> 1));
        const int br = wn * 64 + i * 16 + ln;
        bfr[i] = *(const bf16x8*)(Bs + br * 64 + (((h * 64 + kb * 16) ^ ((br & 7) << 4)) >> 1));
      }
#pragma unroll
      for (int i = 0; i < 4; ++i)
#pragma unroll
        for (int j = 0; j < 4; ++j)
          acc[i][j] = __builtin_amdgcn_mfma_f32_16x16x32_bf16(af[i], bfr[j], acc[i][j], 0, 0, 0);
    }
    __syncthreads();
  }

  // epilogue: C/D layout col=lane&15, row=(lane>>4)*4+reg
  const int crow0 = m0 + wm * 64 + kb * 4;
  const int ccol0 = n0 + wn * 64 + ln;
#pragma unroll
  for (int j = 0; j < 4; ++j) {
    const int col = ccol0 + j * 16;
    if (GUARD && col >= N) continue;
    const float bj = bias ? bias[col] : 0.f;
#pragma unroll
    for (int i = 0; i < 4; ++i) {
#pragma unroll
      for (int r = 0; r < 4; ++r) {
        const int row = crow0 + i * 16 + r;
        float v = acc[i][j][r] + bj;
        if (RELU) v = fmaxf(v, 0.f);
        if (OUTBF) ((unsigned short*)Cp)[(size_t)row * N + col] = f2b(v);
        else       ((float*)Cp)[(size_t)row * N + col] = v;
      }
    }
  }
}

// ---------------- MFMA causal attention, one block per (b,h), bf16 in ------
__global__ __launch_bounds__(256) void attn_mfma_k(const unsigned short* __restrict__ Q,
                                                   const unsigned short* __restrict__ Kg,
                                                   const unsigned short* __restrict__ Vg,
                                                   float* __restrict__ O) {
  constexpr int KSS = 72, VTS = 232, PSS = 232;
  __shared__ unsigned short Ks[208 * KSS];
  __shared__ unsigned short Vt[64 * VTS];
  __shared__ unsigned short Ps[4 * 16 * PSS];
  const int b = blockIdx.x >> 2;
  const int h = blockIdx.x & 3;
  const int tid = threadIdx.x, w = tid >> 6, lane = tid & 63;
  const int kb = lane >> 4;
  const int ln = lane & 15;
  const size_t base = (size_t)b * S * D + h * DH;

  for (int g = tid; g < 200 * 8; g += 256) {
    const int row = g >> 3, gr = g & 7;
    *(bf16x8*)(Ks + row * KSS + gr * 8) = *(const bf16x8*)(Kg + base + (size_t)row * D + gr * 8);
  }
  for (int g = tid; g < 200 * 8; g += 256) {
    const int row = g >> 3, d0 = (g & 7) * 8;
    const bf16x8 v = *(const bf16x8*)(Vg + base + (size_t)row * D + d0);
#pragma unroll
    for (int i = 0; i < 8; ++i) Vt[(d0 + i) * VTS + row] = (unsigned short)v[i];
  }
  if (tid < 64 * 3) {
    const int d = tid / 3, g = tid % 3;
    *(bf16x8*)(Vt + d * VTS + 200 + g * 8) = (bf16x8)0;
  }
  unsigned short* Pw = Ps + w * 16 * PSS;
  if (lane < 32) {
    const int row = lane >> 1, g = lane & 1;
    *(bf16x8*)(Pw + row * PSS + 208 + g * 8) = (bf16x8)0;
  }
  __syncthreads();

  for (int q0 = w * 16; q0 < S; q0 += 64) {
    int qr = q0 + ln; if (qr > S - 1) qr = S - 1;
    const unsigned short* qp = Q + base + (size_t)qr * D + kb * 8;
    const bf16x8 aq0 = *(const bf16x8*)(qp);
    const bf16x8 aq1 = *(const bf16x8*)(qp + 32);
    f32x4 sc[13];
#pragma unroll
    for (int t = 0; t < 13; ++t) {
      const bf16x8 b0 = *(const bf16x8*)(Ks + (t * 16 + ln) * KSS + kb * 8);
      const bf16x8 b1 = *(const bf16x8*)(Ks + (t * 16 + ln) * KSS + 32 + kb * 8);
      f32x4 a = {0.f, 0.f, 0.f, 0.f};
      a = __builtin_amdgcn_mfma_f32_16x16x32_bf16(aq0, b0, a, 0, 0, 0);
      a = __builtin_amdgcn_mfma_f32_16x16x32_bf16(aq1, b1, a, 0, 0, 0);
      sc[t] = a;
    }
    float inv[4];
#pragma unroll
    for (int r = 0; r < 4; ++r) {
      const int q = q0 + kb * 4 + r;
      float m = -1e30f;
#pragma unroll
      for (int t = 0; t < 13; ++t) {
        const int j = t * 16 + ln;
        float s = sc[t][r] * SCALE;
        s = (j <= q) ? s : -1e30f;
        sc[t][r] = s;
        m = fmaxf(m, s);
      }
      m = fmaxf(m, __shfl_xor(m, 1));
      m = fmaxf(m, __shfl_xor(m, 2));
      m = fmaxf(m, __shfl_xor(m, 4));
      m = fmaxf(m, __shfl_xor(m, 8));
      float sm = 0.f;
#pragma unroll
      for (int t = 0; t < 13; ++t) {
        const float e = __expf(sc[t][r] - m);
        sm += e;
        Pw[(kb * 4 + r) * PSS + t * 16 + ln] = f2b(e);
      }
      sm += __shfl_xor(sm, 1);
      sm += __shfl_xor(sm, 2);
      sm += __shfl_xor(sm, 4);
      sm += __shfl_xor(sm, 8);
      inv[r] = 1.f / sm;
    }
#pragma unroll
    for (int ct = 0; ct < 4; ++ct) {
      f32x4 a = {0.f, 0.f, 0.f, 0.f};
#pragma unroll
      for (int kt = 0; kt < 7; ++kt) {
        const bf16x8 pa = *(const bf16x8*)(Pw + ln * PSS + kt * 32 + kb * 8);
        const bf16x8 vb = *(const bf16x8*)(Vt + (ct * 16 + ln) * VTS + kt * 32 + kb * 8);
        a = __builtin_amdgcn_mfma_f32_16x16x32_bf16(pa, vb, a, 0, 0, 0);
      }
#pragma unroll
      for (int r = 0; r < 4; ++r) {
        const int q = q0 + kb * 4 + r;
        if (q < S) O[base + (size_t)q * D + ct * 16 + ln] = a[r] * inv[r];
      }
    }
  }
}

// ---------------------------------------------------------------------------
extern "C" void kernel_launch(void* const* d_in, const int* in_sizes, int n_in,
                              void* d_out, int out_size, void* d_ws, size_t ws_size,
                              hipStream_t stream) {
  const int* ids        = (const int*)d_in[0];
  const float* item_emb = (const float*)d_in[1];
  const float* pos_emb  = (const float*)d_in[2];
  const float* ln1_g    = (const float*)d_in[3];
  const float* ln1_b    = (const float*)d_in[4];
  const float* wq       = (const float*)d_in[5];
  const float* bq       = (const float*)d_in[6];
  const float* wk       = (const float*)d_in[7];
  const float* bk       = (const float*)d_in[8];
  const float* wv       = (const float*)d_in[9];
  const float* bv       = (const float*)d_in[10];
  const float* ln2_g    = (const float*)d_in[11];
  const float* ln2_b    = (const float*)d_in[12];
  const float* wd       = (const float*)d_in[13];
  const float* bd       = (const float*)d_in[14];
  const float* seq_g    = (const float*)d_in[15];
  const float* seq_b    = (const float*)d_in[16];
  const float* w_out    = (const float*)d_in[17];
  float* out = (float*)d_out;

  // ---- workspace layout (bytes), total 524,369,920 ----
  char* wsb = (char*)d_ws;
  float* seq             = (float*)(wsb + 0);
  float* xo              = (float*)(wsb + 104857600);
  unsigned short* seq_bf = (unsigned short*)(wsb + 209715200);
  unsigned short* x_bf   = (unsigned short*)(wsb + 262144000);
  unsigned short* q_bf   = (unsigned short*)(wsb + 314572800);
  unsigned short* k_bf   = (unsigned short*)(wsb + 367001600);
  unsigned short* v_bf   = (unsigned short*)(wsb + 419430400);
  float* y               = (float*)(wsb + 367001600);  // overlays k_bf+v_bf (dead then)
  unsigned short* wob    = (unsigned short*)(wsb + 471859200);
  unsigned short* wtb    = (unsigned short*)(wsb + 523059200);
  unsigned short* semb   = (unsigned short*)(wsb + 524107776);

  const int M = B * S;  // 102400
  const dim3 hgrid(2, 800);   // x=n-tiles (A-tile shared by consecutive blocks)
  const int ln_grid = (M + 3) / 4;

  cvt_wout_k<<<2048, 256, 0, stream>>>(w_out, wob);
  cvt_wt_k<<<512, 256, 0, stream>>>(wq, wk, wv, wd, wtb);
  embed_k<<<2048, 256, 0, stream>>>(ids, item_emb, pos_emb, seq, seq_bf);

  for (int blk = 0; blk < 2; ++blk) {
    const float* l1g = ln1_g + blk * D;
    const float* l1b = ln1_b + blk * D;
    const float* l2g = ln2_g + blk * D;
    const float* l2b = ln2_b + blk * D;
    const unsigned short* WT = wtb + (size_t)blk * 4 * 65536;  // order: q,k,v,d

    bgemm_k<0, 0, 0, 1><<<hgrid, 256, 0, stream>>>(seq_bf, WT + 1 * 65536, bk + blk * D, k_bf, M, D);
    bgemm_k<0, 0, 0, 1><<<hgrid, 256, 0, stream>>>(seq_bf, WT + 2 * 65536, bv + blk * D, v_bf, M, D);
    ln_k<<<ln_grid, 256, 0, stream>>>(seq, D, l1g, l1b, nullptr, xo, x_bf, M);
    bgemm_k<0, 0, 0, 1><<<hgrid, 256, 0, stream>>>(x_bf, WT + 0 * 65536, bq + blk * D, q_bf, M, D);
    attn_mfma_k<<<B * H, 256, 0, stream>>>(q_bf, k_bf, v_bf, xo);
    ln_k<<<ln_grid, 256, 0, stream>>>(seq, D, l1g, l1b, xo, xo, nullptr, M);   // x2 = ln1+o
    ln_k<<<ln_grid, 256, 0, stream>>>(xo, D, l2g, l2b, nullptr, nullptr, x_bf, M);  // t = ln2(x2)
    bgemm_k<0, 0, 1, 0><<<hgrid, 256, 0, stream>>>(x_bf, WT + 3 * 65536, bd + blk * D, y, M, D);
    upd_k<<<2048, 256, 0, stream>>>(y, xo, ids, seq, seq_bf);
  }

  ln_k<<<(B + 3) / 4, 256, 0, stream>>>(seq + (size_t)(S - 1) * D, (size_t)S * D,
                                        seq_g, seq_b, nullptr, nullptr, semb, B);
  // logits: grid x=m-tiles(4) so consecutive blocks share the w_out n-panel
  bgemm_k<1, 1, 0, 0><<<dim3(4, 782), 256, 0, stream>>>(semb, wob, nullptr, out, B, NI);
}

// Round 5
// 973.836 us; speedup vs baseline: 4.9733x; 1.2761x over previous
//
#include <hip/hip_runtime.h>
#include <hip/hip_bf16.h>
#include <cstdint>
#include <cstddef>

namespace {
constexpr int B = 512, S = 200, D = 256, H = 4, DH = 64, NI = 100000;
constexpr float EPS = 1e-3f;
constexpr float SCALE = 0.125f;  // 1/sqrt(DH)
}

typedef __attribute__((ext_vector_type(8))) short bf16x8;
typedef __attribute__((ext_vector_type(4))) float f32x4;

__device__ inline unsigned short f2b(float f) {
  union { float f; unsigned int u; } v; v.f = f;
  unsigned int r = v.u + 0x7FFFu + ((v.u >> 16) & 1u);
  return (unsigned short)(r >> 16);
}

__device__ inline bf16x8 pack8(float4 a, float4 b) {
  bf16x8 r;
  r[0] = (short)f2b(a.x); r[1] = (short)f2b(a.y); r[2] = (short)f2b(a.z); r[3] = (short)f2b(a.w);
  r[4] = (short)f2b(b.x); r[5] = (short)f2b(b.y); r[6] = (short)f2b(b.z); r[7] = (short)f2b(b.w);
  return r;
}

__device__ inline ushort4 pack4(float4 a) {
  ushort4 r;
  r.x = f2b(a.x); r.y = f2b(a.y); r.z = f2b(a.z); r.w = f2b(a.w);
  return r;
}

__device__ inline void gload_lds16(const unsigned short* g, unsigned short* l) {
  __builtin_amdgcn_global_load_lds((const __attribute__((address_space(1))) void*)g,
                                   (__attribute__((address_space(3))) void*)l, 16, 0, 0);
}

// ---------------- weight prep: w_out fp32 [NI][256] -> bf16 same layout ----
__global__ void cvt_wout_k(const float* __restrict__ src, unsigned short* __restrict__ dst) {
  const int total = NI * D / 8;
  for (int i = blockIdx.x * blockDim.x + threadIdx.x; i < total; i += gridDim.x * blockDim.x) {
    const float4 a = *(const float4*)(src + (size_t)i * 8);
    const float4 b = *(const float4*)(src + (size_t)i * 8 + 4);
    *(bf16x8*)(dst + (size_t)i * 8) = pack8(a, b);
  }
}

// ------- hidden weights [K][N] fp32 -> WT bf16 [w][N][K], w = blk*4+{q,k,v,d}
__global__ void cvt_wt_k(const float* __restrict__ wq, const float* __restrict__ wk,
                         const float* __restrict__ wv, const float* __restrict__ wd,
                         unsigned short* __restrict__ dst) {
  const int t = blockIdx.x * 256 + threadIdx.x;  // 131072 total
  const int w = t >> 14, rem = t & 16383;
  const int k = rem >> 6, n4 = (rem & 63) * 4;
  const int blk = w >> 2, which = w & 3;
  const float* src = (which == 0 ? wq : which == 1 ? wk : which == 2 ? wv : wd) + blk * 65536;
  const float4 v = *(const float4*)(src + k * 256 + n4);
  unsigned short* d = dst + w * 65536;
  d[(n4 + 0) * 256 + k] = f2b(v.x);
  d[(n4 + 1) * 256 + k] = f2b(v.y);
  d[(n4 + 2) * 256 + k] = f2b(v.z);
  d[(n4 + 3) * 256 + k] = f2b(v.w);
}

// ---------------- embedding gather + positional add (fp32 + bf16 out) ------
__global__ void embed_k(const int* __restrict__ ids, const float* __restrict__ ie,
                        const float* __restrict__ pe, float* __restrict__ seq,
                        unsigned short* __restrict__ seq_bf) {
  const int total = B * S * (D / 4);
  for (int i = blockIdx.x * blockDim.x + threadIdx.x; i < total; i += gridDim.x * blockDim.x) {
    const int bs = i >> 6;
    const int d4 = (i & 63) << 2;
    const int id = ids[bs];
    const int s = bs % S;
    float4 a = *(const float4*)(ie + (size_t)id * D + d4);
    const float4 p = *(const float4*)(pe + (size_t)s * D + d4);
    a.x += p.x; a.y += p.y; a.z += p.z; a.w += p.w;
    *(float4*)(seq + (size_t)bs * D + d4) = a;
    *(ushort4*)(seq_bf + (size_t)bs * D + d4) = pack4(a);
  }
}

// ---------------- wave-per-row LayerNorm, optional fp32/bf16 outs ----------
__global__ __launch_bounds__(256) void ln_k(const float* __restrict__ in, size_t in_stride,
                                            const float* __restrict__ g, const float* __restrict__ b,
                                            const float* __restrict__ res, float* __restrict__ out_f,
                                            unsigned short* __restrict__ out_bf, int nrows) {
  const int row = blockIdx.x * 4 + (threadIdx.x >> 6);
  if (row >= nrows) return;
  const int lane = threadIdx.x & 63;
  const float4 v = *(const float4*)(in + (size_t)row * in_stride + (lane << 2));
  float s = v.x + v.y + v.z + v.w;
  float ss = v.x * v.x + v.y * v.y + v.z * v.z + v.w * v.w;
#pragma unroll
  for (int off = 32; off; off >>= 1) {
    s += __shfl_xor(s, off);
    ss += __shfl_xor(ss, off);
  }
  const float mean = s * (1.f / D);
  const float rs = rsqrtf(ss * (1.f / D) - mean * mean + EPS);
  const float4 gv = *(const float4*)(g + (lane << 2));
  const float4 bv = *(const float4*)(b + (lane << 2));
  float4 o;
  o.x = (v.x - mean) * rs * gv.x + bv.x;
  o.y = (v.y - mean) * rs * gv.y + bv.y;
  o.z = (v.z - mean) * rs * gv.z + bv.z;
  o.w = (v.w - mean) * rs * gv.w + bv.w;
  if (res) {
    const float4 r = *(const float4*)(res + (size_t)row * D + (lane << 2));
    o.x += r.x; o.y += r.y; o.z += r.z; o.w += r.w;
  }
  if (out_f) *(float4*)(out_f + (size_t)row * D + (lane << 2)) = o;
  if (out_bf) *(ushort4*)(out_bf + (size_t)row * D + (lane << 2)) = pack4(o);
}

// ------- fused: x2 = ln1(seq)+o ; t = ln2(x2). o_x2: in o, out x2. ---------
__global__ __launch_bounds__(256) void ln2x_k(const float* __restrict__ seq,
                                              float* __restrict__ o_x2,
                                              const float* __restrict__ g1, const float* __restrict__ b1,
                                              const float* __restrict__ g2, const float* __restrict__ b2,
                                              unsigned short* __restrict__ t_bf, int nrows) {
  const int row = blockIdx.x * 4 + (threadIdx.x >> 6);
  if (row >= nrows) return;
  const int lane = threadIdx.x & 63;
  const float4 v = *(const float4*)(seq + (size_t)row * D + (lane << 2));
  float s = v.x + v.y + v.z + v.w;
  float ss = v.x * v.x + v.y * v.y + v.z * v.z + v.w * v.w;
#pragma unroll
  for (int off = 32; off; off >>= 1) {
    s += __shfl_xor(s, off);
    ss += __shfl_xor(ss, off);
  }
  const float mean = s * (1.f / D);
  const float rs = rsqrtf(ss * (1.f / D) - mean * mean + EPS);
  const float4 g1v = *(const float4*)(g1 + (lane << 2));
  const float4 b1v = *(const float4*)(b1 + (lane << 2));
  const float4 ov = *(const float4*)(o_x2 + (size_t)row * D + (lane << 2));
  float4 x2;
  x2.x = (v.x - mean) * rs * g1v.x + b1v.x + ov.x;
  x2.y = (v.y - mean) * rs * g1v.y + b1v.y + ov.y;
  x2.z = (v.z - mean) * rs * g1v.z + b1v.z + ov.z;
  x2.w = (v.w - mean) * rs * g1v.w + b1v.w + ov.w;
  float s2 = x2.x + x2.y + x2.z + x2.w;
  float ss2 = x2.x * x2.x + x2.y * x2.y + x2.z * x2.z + x2.w * x2.w;
#pragma unroll
  for (int off = 32; off; off >>= 1) {
    s2 += __shfl_xor(s2, off);
    ss2 += __shfl_xor(ss2, off);
  }
  const float mean2 = s2 * (1.f / D);
  const float rs2 = rsqrtf(ss2 * (1.f / D) - mean2 * mean2 + EPS);
  const float4 g2v = *(const float4*)(g2 + (lane << 2));
  const float4 b2v = *(const float4*)(b2 + (lane << 2));
  float4 t;
  t.x = (x2.x - mean2) * rs2 * g2v.x + b2v.x;
  t.y = (x2.y - mean2) * rs2 * g2v.y + b2v.y;
  t.z = (x2.z - mean2) * rs2 * g2v.z + b2v.z;
  t.w = (x2.w - mean2) * rs2 * g2v.w + b2v.w;
  *(float4*)(o_x2 + (size_t)row * D + (lane << 2)) = x2;
  *(ushort4*)(t_bf + (size_t)row * D + (lane << 2)) = pack4(t);
}

// ---------------- bf16 MFMA GEMM: C[M,N] = A[M,256] @ Wt^T (+bias) ---------
// UPD=1: epilogue computes seq=(relu(y)+x2)*mask -> Cp (f32) + Cbf (bf16).
template <int NSWAP, int GUARD, int RELU, int OUTBF, int UPD>
__global__ __launch_bounds__(256) void bgemm_k(const unsigned short* __restrict__ A,
                                               const unsigned short* __restrict__ Wt,
                                               const float* __restrict__ bias,
                                               void* __restrict__ Cp, int M, int N,
                                               const float* __restrict__ x2,
                                               const int* __restrict__ ids,
                                               unsigned short* __restrict__ Cbf) {
  __shared__ unsigned short As[128 * 64];
  __shared__ unsigned short Bs[128 * 64];
  const int tid = threadIdx.x, w = tid >> 6, lane = tid & 63;
  const int kb = lane >> 4, ln = lane & 15;
  const int m0 = (NSWAP ? blockIdx.x : blockIdx.y) * 128;
  const int n0 = (NSWAP ? blockIdx.y : blockIdx.x) * 128;
  const int wm = w & 1, wn = w >> 1;
  const int rl = lane >> 3;
  const int cb = (lane & 7) << 4;

  f32x4 acc[4][4];
#pragma unroll
  for (int i = 0; i < 4; ++i)
#pragma unroll
    for (int j = 0; j < 4; ++j) acc[i][j] = (f32x4){0.f, 0.f, 0.f, 0.f};

  for (int ks = 0; ks < 4; ++ks) {
    const int ko = ks * 64;
#pragma unroll
    for (int c = 0; c < 4; ++c) {
      const int arow = w * 32 + c * 8 + rl;
      const int sw = (arow & 7) << 4;
      const int cu = (cb ^ sw) >> 1;
      gload_lds16(A + (size_t)(m0 + arow) * 256 + ko + cu, As + (w * 32 + c * 8) * 64);
      int br = n0 + arow;
      if (GUARD && br > N - 1) br = N - 1;
      gload_lds16(Wt + (size_t)br * 256 + ko + cu, Bs + (w * 32 + c * 8) * 64);
    }
    __syncthreads();
#pragma unroll
    for (int h = 0; h < 2; ++h) {
      bf16x8 af[4], bfr[4];
#pragma unroll
      for (int i = 0; i < 4; ++i) {
        const int ar = wm * 64 + i * 16 + ln;
        af[i] = *(const bf16x8*)(As + ar * 64 + (((h * 64 + kb * 16) ^ ((ar & 7) << 4)) >> 1));
        const int br = wn * 64 + i * 16 + ln;
        bfr[i] = *(const bf16x8*)(Bs + br * 64 + (((h * 64 + kb * 16) ^ ((br & 7) << 4)) >> 1));
      }
#pragma unroll
      for (int i = 0; i < 4; ++i)
#pragma unroll
        for (int j = 0; j < 4; ++j)
          acc[i][j] = __builtin_amdgcn_mfma_f32_16x16x32_bf16(af[i], bfr[j], acc[i][j], 0, 0, 0);
    }
    __syncthreads();
  }

  const int crow0 = m0 + wm * 64 + kb * 4;
  const int ccol0 = n0 + wn * 64 + ln;
  float mk[4][4];
  if (UPD) {
#pragma unroll
    for (int i = 0; i < 4; ++i)
#pragma unroll
      for (int r = 0; r < 4; ++r) mk[i][r] = (ids[crow0 + i * 16 + r] != NI) ? 1.f : 0.f;
  }
#pragma unroll
  for (int j = 0; j < 4; ++j) {
    const int col = ccol0 + j * 16;
    if (GUARD && col >= N) continue;
    const float bj = bias ? bias[col] : 0.f;
#pragma unroll
    for (int i = 0; i < 4; ++i) {
#pragma unroll
      for (int r = 0; r < 4; ++r) {
        const int row = crow0 + i * 16 + r;
        float v = acc[i][j][r] + bj;
        if (RELU) v = fmaxf(v, 0.f);
        if (UPD) {
          const float sv = (v + x2[(size_t)row * N + col]) * mk[i][r];
          ((float*)Cp)[(size_t)row * N + col] = sv;
          Cbf[(size_t)row * N + col] = f2b(sv);
        } else if (OUTBF) {
          ((unsigned short*)Cp)[(size_t)row * N + col] = f2b(v);
        } else {
          ((float*)Cp)[(size_t)row * N + col] = v;
        }
      }
    }
  }
}

// ---------------- MFMA causal attention v2: fragment-major LDS -------------
// All MFMA operand reads are lane-ordered 16B granules (conflict-free).
// LDS 79,872 B -> 2 blocks/CU. K staged via per-lane-source global_load_lds.
// Keys 192..207 tail: K=32 MFMA with zeroed upper (kb>=2) fragments.
// FIX (r4 NaN): Vt tail granules for keys 200..207 were never staged ->
// uninitialized LDS; P=0 x NaN-garbage = NaN. Explicitly zeroed below.
__global__ __launch_bounds__(256) void attn2_k(const unsigned short* __restrict__ Q,
                                               const unsigned short* __restrict__ Kg,
                                               const unsigned short* __restrict__ Vg,
                                               float* __restrict__ O) {
  __shared__ unsigned short Ks[13312];      // [t*2+h][lane] granules of 8
  __shared__ unsigned short Vt[13312];      // frag-major V^T + 192..207 half tiles
  __shared__ unsigned short Ps[4 * 3328];   // per-wave P, 208 keys
  const int b = blockIdx.x >> 2;
  const int h = blockIdx.x & 3;
  const int tid = threadIdx.x, w = tid >> 6, lane = tid & 63;
  const int kb = lane >> 4, ln = lane & 15;
  const size_t base = (size_t)b * S * D + h * DH;

  // ---- stage K fragment-major: set s=(t,h2), lane (kb,ln) -> granule ----
  for (int s = w; s < 26; s += 4) {
    const int t = s >> 1, h2 = s & 1;
    int krow = t * 16 + ln; if (krow > S - 1) krow = S - 1;
    gload_lds16(Kg + base + (size_t)krow * D + h2 * 32 + kb * 8, Ks + s * 512);
  }
  // ---- stage V^T fragment-major (transpose via scalar writes) ----
  for (int g = tid; g < 200 * 8; g += 256) {
    const int key = g >> 3, d0 = (g & 7) * 8;
    const bf16x8 v = *(const bf16x8*)(Vg + base + (size_t)key * D + d0);
#pragma unroll
    for (int i = 0; i < 8; ++i) {
      const int d = d0 + i, ct = d >> 4, cl = d & 15;
      int addr;
      if (key < 192) addr = (((ct * 6 + (key >> 5)) * 4 + ((key >> 3) & 3)) * 16 + cl) * 8 + (key & 7);
      else           addr = 12288 + ((ct * 2 + ((key >> 3) & 1)) * 16 + cl) * 8 + (key & 7);
      Vt[addr] = (unsigned short)v[i];
    }
  }
  // ---- zero Vt tail granules for keys 200..207 (never staged) ----
  if (tid < 64) {
    const int ct = tid >> 4, cl = tid & 15;
    *(bf16x8*)(Vt + 12288 + ((ct * 2 + 1) * 16 + cl) * 8) = (bf16x8)0;
  }
  __syncthreads();
  unsigned short* Pw = Ps + w * 3328;

  for (int q0 = w * 16; q0 < S; q0 += 64) {
    int qr = q0 + ln; if (qr > S - 1) qr = S - 1;
    const unsigned short* qp = Q + base + (size_t)qr * D + kb * 8;
    const bf16x8 aq0 = *(const bf16x8*)(qp);
    const bf16x8 aq1 = *(const bf16x8*)(qp + 32);
    // ---- QK^T: 13 key-tiles of 16, conflict-free granule reads ----
    f32x4 sc[13];
#pragma unroll
    for (int t = 0; t < 13; ++t) {
      f32x4 a = {0.f, 0.f, 0.f, 0.f};
      a = __builtin_amdgcn_mfma_f32_16x16x32_bf16(aq0, *(const bf16x8*)(Ks + (t * 2 + 0) * 512 + lane * 8), a, 0, 0, 0);
      a = __builtin_amdgcn_mfma_f32_16x16x32_bf16(aq1, *(const bf16x8*)(Ks + (t * 2 + 1) * 512 + lane * 8), a, 0, 0, 0);
      sc[t] = a;
    }
    // ---- softmax per row-group; P -> fragment-major LDS ----
    float inv[4];
#pragma unroll
    for (int r = 0; r < 4; ++r) {
      const int q = q0 + kb * 4 + r;
      const int qrow = kb * 4 + r;
      float m = -1e30f;
#pragma unroll
      for (int t = 0; t < 13; ++t) {
        const int j = t * 16 + ln;
        float s = sc[t][r] * SCALE;
        s = (j <= q) ? s : -1e30f;
        sc[t][r] = s;
        m = fmaxf(m, s);
      }
      m = fmaxf(m, __shfl_xor(m, 1));
      m = fmaxf(m, __shfl_xor(m, 2));
      m = fmaxf(m, __shfl_xor(m, 4));
      m = fmaxf(m, __shfl_xor(m, 8));
      float sm = 0.f;
#pragma unroll
      for (int t = 0; t < 13; ++t) {
        const float e = __expf(sc[t][r] - m);
        sm += e;
        int addr;
        if (t < 12) addr = (((t >> 1) * 4 + ((2 * t + (ln >> 3)) & 3)) * 16 + qrow) * 8 + (ln & 7);
        else        addr = 3072 + ((ln >> 3) * 16 + qrow) * 8 + (ln & 7);
        Pw[addr] = f2b(e);
      }
      sm += __shfl_xor(sm, 1);
      sm += __shfl_xor(sm, 2);
      sm += __shfl_xor(sm, 4);
      sm += __shfl_xor(sm, 8);
      inv[r] = 1.f / sm;
    }
    // ---- PV: 4 d-tiles x (6 full K=32 tiles + 16-key tail) ----
#pragma unroll
    for (int ct = 0; ct < 4; ++ct) {
      f32x4 a = {0.f, 0.f, 0.f, 0.f};
#pragma unroll
      for (int kt = 0; kt < 6; ++kt) {
        const bf16x8 pa = *(const bf16x8*)(Pw + ((kt * 4 + kb) * 16 + ln) * 8);
        const bf16x8 vb = *(const bf16x8*)(Vt + (((ct * 6 + kt) * 4 + kb) * 16 + ln) * 8);
        a = __builtin_amdgcn_mfma_f32_16x16x32_bf16(pa, vb, a, 0, 0, 0);
      }
      {
        bf16x8 pa = (bf16x8)0, vb = (bf16x8)0;
        if (kb < 2) {
          pa = *(const bf16x8*)(Pw + 3072 + (kb * 16 + ln) * 8);
          vb = *(const bf16x8*)(Vt + 12288 + ((ct * 2 + kb) * 16 + ln) * 8);
        }
        a = __builtin_amdgcn_mfma_f32_16x16x32_bf16(pa, vb, a, 0, 0, 0);
      }
#pragma unroll
      for (int r = 0; r < 4; ++r) {
        const int q = q0 + kb * 4 + r;
        if (q < S) O[base + (size_t)q * D + ct * 16 + ln] = a[r] * inv[r];
      }
    }
  }
}

// ---------------------------------------------------------------------------
extern "C" void kernel_launch(void* const* d_in, const int* in_sizes, int n_in,
                              void* d_out, int out_size, void* d_ws, size_t ws_size,
                              hipStream_t stream) {
  const int* ids        = (const int*)d_in[0];
  const float* item_emb = (const float*)d_in[1];
  const float* pos_emb  = (const float*)d_in[2];
  const float* ln1_g    = (const float*)d_in[3];
  const float* ln1_b    = (const float*)d_in[4];
  const float* wq       = (const float*)d_in[5];
  const float* bq       = (const float*)d_in[6];
  const float* wk       = (const float*)d_in[7];
  const float* bk       = (const float*)d_in[8];
  const float* wv       = (const float*)d_in[9];
  const float* bv       = (const float*)d_in[10];
  const float* ln2_g    = (const float*)d_in[11];
  const float* ln2_b    = (const float*)d_in[12];
  const float* wd       = (const float*)d_in[13];
  const float* bd       = (const float*)d_in[14];
  const float* seq_g    = (const float*)d_in[15];
  const float* seq_b    = (const float*)d_in[16];
  const float* w_out    = (const float*)d_in[17];
  float* out = (float*)d_out;

  // ---- workspace layout (bytes) ----
  char* wsb = (char*)d_ws;
  float* seq             = (float*)(wsb + 0);
  float* xo              = (float*)(wsb + 104857600);   // o -> x2
  unsigned short* seq_bf = (unsigned short*)(wsb + 209715200);
  unsigned short* x_bf   = (unsigned short*)(wsb + 262144000);
  unsigned short* q_bf   = (unsigned short*)(wsb + 314572800);
  unsigned short* k_bf   = (unsigned short*)(wsb + 367001600);
  unsigned short* v_bf   = (unsigned short*)(wsb + 419430400);
  unsigned short* wob    = (unsigned short*)(wsb + 471859200);
  unsigned short* wtb    = (unsigned short*)(wsb + 523059200);
  unsigned short* semb   = (unsigned short*)(wsb + 524107776);

  const int M = B * S;  // 102400
  const dim3 hgrid(2, 800);
  const int ln_grid = (M + 3) / 4;

  cvt_wout_k<<<2048, 256, 0, stream>>>(w_out, wob);
  cvt_wt_k<<<512, 256, 0, stream>>>(wq, wk, wv, wd, wtb);
  embed_k<<<2048, 256, 0, stream>>>(ids, item_emb, pos_emb, seq, seq_bf);

  for (int blk = 0; blk < 2; ++blk) {
    const float* l1g = ln1_g + blk * D;
    const float* l1b = ln1_b + blk * D;
    const float* l2g = ln2_g + blk * D;
    const float* l2b = ln2_b + blk * D;
    const unsigned short* WT = wtb + (size_t)blk * 4 * 65536;  // order: q,k,v,d

    bgemm_k<0, 0, 0, 1, 0><<<hgrid, 256, 0, stream>>>(seq_bf, WT + 1 * 65536, bk + blk * D, k_bf, M, D, nullptr, nullptr, nullptr);
    bgemm_k<0, 0, 0, 1, 0><<<hgrid, 256, 0, stream>>>(seq_bf, WT + 2 * 65536, bv + blk * D, v_bf, M, D, nullptr, nullptr, nullptr);
    ln_k<<<ln_grid, 256, 0, stream>>>(seq, D, l1g, l1b, nullptr, nullptr, x_bf, M);
    bgemm_k<0, 0, 0, 1, 0><<<hgrid, 256, 0, stream>>>(x_bf, WT + 0 * 65536, bq + blk * D, q_bf, M, D, nullptr, nullptr, nullptr);
    attn2_k<<<B * H, 256, 0, stream>>>(q_bf, k_bf, v_bf, xo);
    ln2x_k<<<ln_grid, 256, 0, stream>>>(seq, xo, l1g, l1b, l2g, l2b, x_bf, M);
    bgemm_k<0, 0, 1, 0, 1><<<hgrid, 256, 0, stream>>>(x_bf, WT + 3 * 65536, bd + blk * D, seq, M, D, xo, ids, seq_bf);
  }

  ln_k<<<(B + 3) / 4, 256, 0, stream>>>(seq + (size_t)(S - 1) * D, (size_t)S * D,
                                        seq_g, seq_b, nullptr, nullptr, semb, B);
  bgemm_k<1, 1, 0, 0, 0><<<dim3(4, 782), 256, 0, stream>>>(semb, wob, nullptr, out, B, NI, nullptr, nullptr, nullptr);
}

// Round 6
// 841.530 us; speedup vs baseline: 5.7552x; 1.1572x over previous
//
#include <hip/hip_runtime.h>
#include <hip/hip_bf16.h>
#include <cstdint>
#include <cstddef>

namespace {
constexpr int B = 512, S = 200, D = 256, H = 4, DH = 64, NI = 100000;
constexpr float EPS = 1e-3f;
constexpr float SCALE = 0.125f;  // 1/sqrt(DH)
}

typedef __attribute__((ext_vector_type(8))) short bf16x8;
typedef __attribute__((ext_vector_type(4))) float f32x4;

__device__ inline unsigned short f2b(float f) {
  union { float f; unsigned int u; } v; v.f = f;
  unsigned int r = v.u + 0x7FFFu + ((v.u >> 16) & 1u);
  return (unsigned short)(r >> 16);
}

__device__ inline float b2f(unsigned short u) {
  union { unsigned int i; float f; } x; x.i = (unsigned int)u << 16; return x.f;
}

__device__ inline bf16x8 pack8(float4 a, float4 b) {
  bf16x8 r;
  r[0] = (short)f2b(a.x); r[1] = (short)f2b(a.y); r[2] = (short)f2b(a.z); r[3] = (short)f2b(a.w);
  r[4] = (short)f2b(b.x); r[5] = (short)f2b(b.y); r[6] = (short)f2b(b.z); r[7] = (short)f2b(b.w);
  return r;
}

__device__ inline ushort4 pack4(float4 a) {
  ushort4 r;
  r.x = f2b(a.x); r.y = f2b(a.y); r.z = f2b(a.z); r.w = f2b(a.w);
  return r;
}

__device__ inline float4 unpack4(ushort4 u) {
  float4 r; r.x = b2f(u.x); r.y = b2f(u.y); r.z = b2f(u.z); r.w = b2f(u.w); return r;
}

__device__ inline void gload_lds16(const unsigned short* g, unsigned short* l) {
  __builtin_amdgcn_global_load_lds((const __attribute__((address_space(1))) void*)g,
                                   (__attribute__((address_space(3))) void*)l, 16, 0, 0);
}

// ---------------- weight prep: w_out fp32 [NI][256] -> bf16 same layout ----
__global__ void cvt_wout_k(const float* __restrict__ src, unsigned short* __restrict__ dst) {
  const int total = NI * D / 8;
  for (int i = blockIdx.x * blockDim.x + threadIdx.x; i < total; i += gridDim.x * blockDim.x) {
    const float4 a = *(const float4*)(src + (size_t)i * 8);
    const float4 b = *(const float4*)(src + (size_t)i * 8 + 4);
    *(bf16x8*)(dst + (size_t)i * 8) = pack8(a, b);
  }
}

// ------- hidden weights [K][N] fp32 -> WT bf16 [w][N][K], w = blk*4+{q,k,v,d}
__global__ void cvt_wt_k(const float* __restrict__ wq, const float* __restrict__ wk,
                         const float* __restrict__ wv, const float* __restrict__ wd,
                         unsigned short* __restrict__ dst) {
  const int t = blockIdx.x * 256 + threadIdx.x;  // 131072 total
  const int w = t >> 14, rem = t & 16383;
  const int k = rem >> 6, n4 = (rem & 63) * 4;
  const int blk = w >> 2, which = w & 3;
  const float* src = (which == 0 ? wq : which == 1 ? wk : which == 2 ? wv : wd) + blk * 65536;
  const float4 v = *(const float4*)(src + k * 256 + n4);
  unsigned short* d = dst + w * 65536;
  d[(n4 + 0) * 256 + k] = f2b(v.x);
  d[(n4 + 1) * 256 + k] = f2b(v.y);
  d[(n4 + 2) * 256 + k] = f2b(v.z);
  d[(n4 + 3) * 256 + k] = f2b(v.w);
}

// ---------------- embedding gather + positional add -> bf16 seq ------------
__global__ void embed_k(const int* __restrict__ ids, const float* __restrict__ ie,
                        const float* __restrict__ pe, unsigned short* __restrict__ seq_bf) {
  const int total = B * S * (D / 4);
  for (int i = blockIdx.x * blockDim.x + threadIdx.x; i < total; i += gridDim.x * blockDim.x) {
    const int bs = i >> 6;
    const int d4 = (i & 63) << 2;
    const int id = ids[bs];
    const int s = bs % S;
    float4 a = *(const float4*)(ie + (size_t)id * D + d4);
    const float4 p = *(const float4*)(pe + (size_t)s * D + d4);
    a.x += p.x; a.y += p.y; a.z += p.z; a.w += p.w;
    *(ushort4*)(seq_bf + (size_t)bs * D + d4) = pack4(a);
  }
}

// ---------------- wave-per-row LayerNorm, bf16 in -> bf16 out --------------
__global__ __launch_bounds__(256) void ln_bf_k(const unsigned short* __restrict__ in,
                                               size_t in_stride,
                                               const float* __restrict__ g, const float* __restrict__ b,
                                               unsigned short* __restrict__ outp, int nrows) {
  const int row = blockIdx.x * 4 + (threadIdx.x >> 6);
  if (row >= nrows) return;
  const int lane = threadIdx.x & 63;
  const float4 v = unpack4(*(const ushort4*)(in + (size_t)row * in_stride + (lane << 2)));
  float s = v.x + v.y + v.z + v.w;
  float ss = v.x * v.x + v.y * v.y + v.z * v.z + v.w * v.w;
#pragma unroll
  for (int off = 32; off; off >>= 1) {
    s += __shfl_xor(s, off);
    ss += __shfl_xor(ss, off);
  }
  const float mean = s * (1.f / D);
  const float rs = rsqrtf(ss * (1.f / D) - mean * mean + EPS);
  const float4 gv = *(const float4*)(g + (lane << 2));
  const float4 bv = *(const float4*)(b + (lane << 2));
  float4 o;
  o.x = (v.x - mean) * rs * gv.x + bv.x;
  o.y = (v.y - mean) * rs * gv.y + bv.y;
  o.z = (v.z - mean) * rs * gv.z + bv.z;
  o.w = (v.w - mean) * rs * gv.w + bv.w;
  *(ushort4*)(outp + (size_t)row * D + (lane << 2)) = pack4(o);
}

// ------- fused: x2 = x_bf + o_bf (f32 out) ; t = ln2(x2) (bf16, in-place ok)
__global__ __launch_bounds__(256) void ln2x2_k(const unsigned short* __restrict__ x_bf,
                                               const unsigned short* __restrict__ o_bf,
                                               const float* __restrict__ g2, const float* __restrict__ b2,
                                               float* __restrict__ x2_out,
                                               unsigned short* __restrict__ t_bf, int nrows) {
  const int row = blockIdx.x * 4 + (threadIdx.x >> 6);
  if (row >= nrows) return;
  const int lane = threadIdx.x & 63;
  const float4 xv = unpack4(*(const ushort4*)(x_bf + (size_t)row * D + (lane << 2)));
  const float4 ov = unpack4(*(const ushort4*)(o_bf + (size_t)row * D + (lane << 2)));
  float4 x2;
  x2.x = xv.x + ov.x; x2.y = xv.y + ov.y; x2.z = xv.z + ov.z; x2.w = xv.w + ov.w;
  *(float4*)(x2_out + (size_t)row * D + (lane << 2)) = x2;
  float s2 = x2.x + x2.y + x2.z + x2.w;
  float ss2 = x2.x * x2.x + x2.y * x2.y + x2.z * x2.z + x2.w * x2.w;
#pragma unroll
  for (int off = 32; off; off >>= 1) {
    s2 += __shfl_xor(s2, off);
    ss2 += __shfl_xor(ss2, off);
  }
  const float mean2 = s2 * (1.f / D);
  const float rs2 = rsqrtf(ss2 * (1.f / D) - mean2 * mean2 + EPS);
  const float4 g2v = *(const float4*)(g2 + (lane << 2));
  const float4 b2v = *(const float4*)(b2 + (lane << 2));
  float4 t;
  t.x = (x2.x - mean2) * rs2 * g2v.x + b2v.x;
  t.y = (x2.y - mean2) * rs2 * g2v.y + b2v.y;
  t.z = (x2.z - mean2) * rs2 * g2v.z + b2v.z;
  t.w = (x2.w - mean2) * rs2 * g2v.w + b2v.w;
  *(ushort4*)(t_bf + (size_t)row * D + (lane << 2)) = pack4(t);
}

// -------- full-N hidden GEMM: C[M,256] = A[M,256] @ Wt[256,256]^T (+bias) --
// Tile 128 rows x 256 cols, 8 waves (512 thr), wave-tile 64x64, BK=64.
// A read exactly once. XOR-swizzled LDS as in bgemm_k.
// UPD=1: epilogue seq_bf = bf16((relu(y) + x2) * mask).
template <int RELU, int UPD>
__global__ __launch_bounds__(512) void bgemm2_k(const unsigned short* __restrict__ A,
                                                const unsigned short* __restrict__ Wt,
                                                const float* __restrict__ bias,
                                                unsigned short* __restrict__ Cbf,
                                                const float* __restrict__ x2,
                                                const int* __restrict__ ids) {
  __shared__ unsigned short As[128 * 64];   // 16.4 KB
  __shared__ unsigned short Bs[256 * 64];   // 32.8 KB
  const int tid = threadIdx.x, w = tid >> 6, lane = tid & 63;
  const int kb = lane >> 4, ln = lane & 15;
  const int m0 = blockIdx.x * 128;
  const int wm = w & 1, wn = w >> 1;   // 2 x 4 wave grid over 128 x 256

  f32x4 acc[4][4];
#pragma unroll
  for (int i = 0; i < 4; ++i)
#pragma unroll
    for (int j = 0; j < 4; ++j) acc[i][j] = (f32x4){0.f, 0.f, 0.f, 0.f};

  for (int ks = 0; ks < 4; ++ks) {
    const int ko = ks * 64;
    // stage A: 1024 granules of 16B; wave w -> granules (w*2+r)*64 + lane
#pragma unroll
    for (int r = 0; r < 2; ++r) {
      const int g = (w * 2 + r) * 64 + lane;
      const int row = g >> 3, gc = g & 7;
      gload_lds16(A + (size_t)(m0 + row) * 256 + ko + ((gc ^ (row & 7)) << 3),
                  As + (size_t)(w * 2 + r) * 512);
    }
    // stage B: 2048 granules
#pragma unroll
    for (int r = 0; r < 4; ++r) {
      const int g = (w * 4 + r) * 64 + lane;
      const int row = g >> 3, gc = g & 7;
      gload_lds16(Wt + (size_t)row * 256 + ko + ((gc ^ (row & 7)) << 3),
                  Bs + (size_t)(w * 4 + r) * 512);
    }
    __syncthreads();
#pragma unroll
    for (int h = 0; h < 2; ++h) {
      bf16x8 af[4], bfr[4];
#pragma unroll
      for (int i = 0; i < 4; ++i) {
        const int ar = wm * 64 + i * 16 + ln;
        af[i] = *(const bf16x8*)(As + ar * 64 + (((h * 64 + kb * 16) ^ ((ar & 7) << 4)) >> 1));
        const int br = wn * 64 + i * 16 + ln;
        bfr[i] = *(const bf16x8*)(Bs + br * 64 + (((h * 64 + kb * 16) ^ ((br & 7) << 4)) >> 1));
      }
#pragma unroll
      for (int i = 0; i < 4; ++i)
#pragma unroll
        for (int j = 0; j < 4; ++j)
          acc[i][j] = __builtin_amdgcn_mfma_f32_16x16x32_bf16(af[i], bfr[j], acc[i][j], 0, 0, 0);
    }
    __syncthreads();
  }

  const int crow0 = m0 + wm * 64 + kb * 4;
  const int ccol0 = wn * 64 + ln;
  float mk[4][4];
  if (UPD) {
#pragma unroll
    for (int i = 0; i < 4; ++i)
#pragma unroll
      for (int r = 0; r < 4; ++r) mk[i][r] = (ids[crow0 + i * 16 + r] != NI) ? 1.f : 0.f;
  }
#pragma unroll
  for (int j = 0; j < 4; ++j) {
    const int col = ccol0 + j * 16;
    const float bj = bias[col];
#pragma unroll
    for (int i = 0; i < 4; ++i) {
#pragma unroll
      for (int r = 0; r < 4; ++r) {
        const int row = crow0 + i * 16 + r;
        float v = acc[i][j][r] + bj;
        if (RELU) v = fmaxf(v, 0.f);
        if (UPD) v = (v + x2[(size_t)row * 256 + col]) * mk[i][r];
        Cbf[(size_t)row * 256 + col] = f2b(v);
      }
    }
  }
}

// ---------------- bf16 MFMA GEMM (logits): C[M,N] = A @ Wt^T ---------------
template <int NSWAP, int GUARD>
__global__ __launch_bounds__(256) void bgemm_k(const unsigned short* __restrict__ A,
                                               const unsigned short* __restrict__ Wt,
                                               float* __restrict__ C, int M, int N) {
  __shared__ unsigned short As[128 * 64];
  __shared__ unsigned short Bs[128 * 64];
  const int tid = threadIdx.x, w = tid >> 6, lane = tid & 63;
  const int kb = lane >> 4, ln = lane & 15;
  const int m0 = (NSWAP ? blockIdx.x : blockIdx.y) * 128;
  const int n0 = (NSWAP ? blockIdx.y : blockIdx.x) * 128;
  const int wm = w & 1, wn = w >> 1;
  const int rl = lane >> 3;
  const int cb = (lane & 7) << 4;

  f32x4 acc[4][4];
#pragma unroll
  for (int i = 0; i < 4; ++i)
#pragma unroll
    for (int j = 0; j < 4; ++j) acc[i][j] = (f32x4){0.f, 0.f, 0.f, 0.f};

  for (int ks = 0; ks < 4; ++ks) {
    const int ko = ks * 64;
#pragma unroll
    for (int c = 0; c < 4; ++c) {
      const int arow = w * 32 + c * 8 + rl;
      const int sw = (arow & 7) << 4;
      const int cu = (cb ^ sw) >> 1;
      gload_lds16(A + (size_t)(m0 + arow) * 256 + ko + cu, As + (w * 32 + c * 8) * 64);
      int br = n0 + arow;
      if (GUARD && br > N - 1) br = N - 1;
      gload_lds16(Wt + (size_t)br * 256 + ko + cu, Bs + (w * 32 + c * 8) * 64);
    }
    __syncthreads();
#pragma unroll
    for (int h = 0; h < 2; ++h) {
      bf16x8 af[4], bfr[4];
#pragma unroll
      for (int i = 0; i < 4; ++i) {
        const int ar = wm * 64 + i * 16 + ln;
        af[i] = *(const bf16x8*)(As + ar * 64 + (((h * 64 + kb * 16) ^ ((ar & 7) << 4)) >> 1));
        const int br = wn * 64 + i * 16 + ln;
        bfr[i] = *(const bf16x8*)(Bs + br * 64 + (((h * 64 + kb * 16) ^ ((br & 7) << 4)) >> 1));
      }
#pragma unroll
      for (int i = 0; i < 4; ++i)
#pragma unroll
        for (int j = 0; j < 4; ++j)
          acc[i][j] = __builtin_amdgcn_mfma_f32_16x16x32_bf16(af[i], bfr[j], acc[i][j], 0, 0, 0);
    }
    __syncthreads();
  }

  const int crow0 = m0 + wm * 64 + kb * 4;
  const int ccol0 = n0 + wn * 64 + ln;
#pragma unroll
  for (int j = 0; j < 4; ++j) {
    const int col = ccol0 + j * 16;
    if (GUARD && col >= N) continue;
#pragma unroll
    for (int i = 0; i < 4; ++i) {
#pragma unroll
      for (int r = 0; r < 4; ++r) {
        const int row = crow0 + i * 16 + r;
        C[(size_t)row * N + col] = acc[i][j][r];
      }
    }
  }
}

// ---------------- MFMA causal attention v2: fragment-major LDS -------------
// O written as bf16. LDS 79,872 B -> 2 blocks/CU.
__global__ __launch_bounds__(256) void attn2_k(const unsigned short* __restrict__ Q,
                                               const unsigned short* __restrict__ Kg,
                                               const unsigned short* __restrict__ Vg,
                                               unsigned short* __restrict__ O) {
  __shared__ unsigned short Ks[13312];      // [t*2+h][lane] granules of 8
  __shared__ unsigned short Vt[13312];      // frag-major V^T + 192..207 half tiles
  __shared__ unsigned short Ps[4 * 3328];   // per-wave P, 208 keys
  const int b = blockIdx.x >> 2;
  const int h = blockIdx.x & 3;
  const int tid = threadIdx.x, w = tid >> 6, lane = tid & 63;
  const int kb = lane >> 4, ln = lane & 15;
  const size_t base = (size_t)b * S * D + h * DH;

  for (int s = w; s < 26; s += 4) {
    const int t = s >> 1, h2 = s & 1;
    int krow = t * 16 + ln; if (krow > S - 1) krow = S - 1;
    gload_lds16(Kg + base + (size_t)krow * D + h2 * 32 + kb * 8, Ks + s * 512);
  }
  for (int g = tid; g < 200 * 8; g += 256) {
    const int key = g >> 3, d0 = (g & 7) * 8;
    const bf16x8 v = *(const bf16x8*)(Vg + base + (size_t)key * D + d0);
#pragma unroll
    for (int i = 0; i < 8; ++i) {
      const int d = d0 + i, ct = d >> 4, cl = d & 15;
      int addr;
      if (key < 192) addr = (((ct * 6 + (key >> 5)) * 4 + ((key >> 3) & 3)) * 16 + cl) * 8 + (key & 7);
      else           addr = 12288 + ((ct * 2 + ((key >> 3) & 1)) * 16 + cl) * 8 + (key & 7);
      Vt[addr] = (unsigned short)v[i];
    }
  }
  // zero Vt tail granules for keys 200..207 (never staged)
  if (tid < 64) {
    const int ct = tid >> 4, cl = tid & 15;
    *(bf16x8*)(Vt + 12288 + ((ct * 2 + 1) * 16 + cl) * 8) = (bf16x8)0;
  }
  __syncthreads();
  unsigned short* Pw = Ps + w * 3328;

  for (int q0 = w * 16; q0 < S; q0 += 64) {
    int qr = q0 + ln; if (qr > S - 1) qr = S - 1;
    const unsigned short* qp = Q + base + (size_t)qr * D + kb * 8;
    const bf16x8 aq0 = *(const bf16x8*)(qp);
    const bf16x8 aq1 = *(const bf16x8*)(qp + 32);
    f32x4 sc[13];
#pragma unroll
    for (int t = 0; t < 13; ++t) {
      f32x4 a = {0.f, 0.f, 0.f, 0.f};
      a = __builtin_amdgcn_mfma_f32_16x16x32_bf16(aq0, *(const bf16x8*)(Ks + (t * 2 + 0) * 512 + lane * 8), a, 0, 0, 0);
      a = __builtin_amdgcn_mfma_f32_16x16x32_bf16(aq1, *(const bf16x8*)(Ks + (t * 2 + 1) * 512 + lane * 8), a, 0, 0, 0);
      sc[t] = a;
    }
    float inv[4];
#pragma unroll
    for (int r = 0; r < 4; ++r) {
      const int q = q0 + kb * 4 + r;
      const int qrow = kb * 4 + r;
      float m = -1e30f;
#pragma unroll
      for (int t = 0; t < 13; ++t) {
        const int j = t * 16 + ln;
        float s = sc[t][r] * SCALE;
        s = (j <= q) ? s : -1e30f;
        sc[t][r] = s;
        m = fmaxf(m, s);
      }
      m = fmaxf(m, __shfl_xor(m, 1));
      m = fmaxf(m, __shfl_xor(m, 2));
      m = fmaxf(m, __shfl_xor(m, 4));
      m = fmaxf(m, __shfl_xor(m, 8));
      float sm = 0.f;
#pragma unroll
      for (int t = 0; t < 13; ++t) {
        const float e = __expf(sc[t][r] - m);
        sm += e;
        int addr;
        if (t < 12) addr = (((t >> 1) * 4 + ((2 * t + (ln >> 3)) & 3)) * 16 + qrow) * 8 + (ln & 7);
        else        addr = 3072 + ((ln >> 3) * 16 + qrow) * 8 + (ln & 7);
        Pw[addr] = f2b(e);
      }
      sm += __shfl_xor(sm, 1);
      sm += __shfl_xor(sm, 2);
      sm += __shfl_xor(sm, 4);
      sm += __shfl_xor(sm, 8);
      inv[r] = 1.f / sm;
    }
#pragma unroll
    for (int ct = 0; ct < 4; ++ct) {
      f32x4 a = {0.f, 0.f, 0.f, 0.f};
#pragma unroll
      for (int kt = 0; kt < 6; ++kt) {
        const bf16x8 pa = *(const bf16x8*)(Pw + ((kt * 4 + kb) * 16 + ln) * 8);
        const bf16x8 vb = *(const bf16x8*)(Vt + (((ct * 6 + kt) * 4 + kb) * 16 + ln) * 8);
        a = __builtin_amdgcn_mfma_f32_16x16x32_bf16(pa, vb, a, 0, 0, 0);
      }
      {
        bf16x8 pa = (bf16x8)0, vb = (bf16x8)0;
        if (kb < 2) {
          pa = *(const bf16x8*)(Pw + 3072 + (kb * 16 + ln) * 8);
          vb = *(const bf16x8*)(Vt + 12288 + ((ct * 2 + kb) * 16 + ln) * 8);
        }
        a = __builtin_amdgcn_mfma_f32_16x16x32_bf16(pa, vb, a, 0, 0, 0);
      }
#pragma unroll
      for (int r = 0; r < 4; ++r) {
        const int q = q0 + kb * 4 + r;
        if (q < S) O[base + (size_t)q * D + ct * 16 + ln] = f2b(a[r] * inv[r]);
      }
    }
  }
}

// ---------------------------------------------------------------------------
extern "C" void kernel_launch(void* const* d_in, const int* in_sizes, int n_in,
                              void* d_out, int out_size, void* d_ws, size_t ws_size,
                              hipStream_t stream) {
  const int* ids        = (const int*)d_in[0];
  const float* item_emb = (const float*)d_in[1];
  const float* pos_emb  = (const float*)d_in[2];
  const float* ln1_g    = (const float*)d_in[3];
  const float* ln1_b    = (const float*)d_in[4];
  const float* wq       = (const float*)d_in[5];
  const float* bq       = (const float*)d_in[6];
  const float* wk       = (const float*)d_in[7];
  const float* bk       = (const float*)d_in[8];
  const float* wv       = (const float*)d_in[9];
  const float* bv       = (const float*)d_in[10];
  const float* ln2_g    = (const float*)d_in[11];
  const float* ln2_b    = (const float*)d_in[12];
  const float* wd       = (const float*)d_in[13];
  const float* bd       = (const float*)d_in[14];
  const float* seq_g    = (const float*)d_in[15];
  const float* seq_b    = (const float*)d_in[16];
  const float* w_out    = (const float*)d_in[17];
  float* out = (float*)d_out;

  // ---- workspace layout (bytes), end = 524,369,920 ----
  char* wsb = (char*)d_ws;
  unsigned short* o_bf   = (unsigned short*)(wsb + 0);           // 41 MB
  float* x2              = (float*)(wsb + 104857600);            // 104.9 MB
  unsigned short* seq_bf = (unsigned short*)(wsb + 209715200);   // 52.4 MB
  unsigned short* x_bf   = (unsigned short*)(wsb + 262144000);   // ln1 out, then t (in-place)
  unsigned short* q_bf   = (unsigned short*)(wsb + 314572800);
  unsigned short* k_bf   = (unsigned short*)(wsb + 367001600);
  unsigned short* v_bf   = (unsigned short*)(wsb + 419430400);
  unsigned short* wob    = (unsigned short*)(wsb + 471859200);   // 51.2 MB
  unsigned short* wtb    = (unsigned short*)(wsb + 523059200);   // 1.05 MB
  unsigned short* semb   = (unsigned short*)(wsb + 524107776);   // 0.26 MB

  const int M = B * S;  // 102400
  const int ln_grid = (M + 3) / 4;

  cvt_wout_k<<<2048, 256, 0, stream>>>(w_out, wob);
  cvt_wt_k<<<512, 256, 0, stream>>>(wq, wk, wv, wd, wtb);
  embed_k<<<2048, 256, 0, stream>>>(ids, item_emb, pos_emb, seq_bf);

  for (int blk = 0; blk < 2; ++blk) {
    const float* l1g = ln1_g + blk * D;
    const float* l1b = ln1_b + blk * D;
    const float* l2g = ln2_g + blk * D;
    const float* l2b = ln2_b + blk * D;
    const unsigned short* WT = wtb + (size_t)blk * 4 * 65536;  // order: q,k,v,d

    bgemm2_k<0, 0><<<800, 512, 0, stream>>>(seq_bf, WT + 1 * 65536, bk + blk * D, k_bf, nullptr, nullptr);
    bgemm2_k<0, 0><<<800, 512, 0, stream>>>(seq_bf, WT + 2 * 65536, bv + blk * D, v_bf, nullptr, nullptr);
    ln_bf_k<<<ln_grid, 256, 0, stream>>>(seq_bf, D, l1g, l1b, x_bf, M);
    bgemm2_k<0, 0><<<800, 512, 0, stream>>>(x_bf, WT + 0 * 65536, bq + blk * D, q_bf, nullptr, nullptr);
    attn2_k<<<B * H, 256, 0, stream>>>(q_bf, k_bf, v_bf, o_bf);
    ln2x2_k<<<ln_grid, 256, 0, stream>>>(x_bf, o_bf, l2g, l2b, x2, x_bf, M);
    bgemm2_k<1, 1><<<800, 512, 0, stream>>>(x_bf, WT + 3 * 65536, bd + blk * D, seq_bf, x2, ids);
  }

  ln_bf_k<<<(B + 3) / 4, 256, 0, stream>>>(seq_bf + (size_t)(S - 1) * D, (size_t)S * D,
                                           seq_g, seq_b, semb, B);
  bgemm_k<1, 1><<<dim3(4, 782), 256, 0, stream>>>(semb, wob, out, B, NI);
}